// Round 12
// baseline (1194.260 us; speedup 1.0000x reference)
//
#include <hip/hip_runtime.h>

#define BB 8
#define NN 4096
#define KK 10
#define CAP 24
#define TT 4
typedef unsigned long long u64;
typedef __attribute__((ext_vector_type(8))) short bf16x8;
typedef __attribute__((ext_vector_type(4))) float f32x4;

__device__ __forceinline__ float lrelu(float v){ return v >= 0.f ? v : 0.2f*v; }
__device__ __forceinline__ unsigned fenc(float f){
  unsigned u = __float_as_uint(f);
  return u ^ (((unsigned)((int)u >> 31)) | 0x80000000u);
}
__device__ __forceinline__ float fdec(unsigned e){
  return (e & 0x80000000u) ? __uint_as_float(e & 0x7fffffffu) : __uint_as_float(~e);
}

// ---------------- weight prep: transposes + split-bf16 conversions ----------------
__global__ __launch_bounds__(256) void prep_k(
    const float* __restrict__ W1, const float* __restrict__ W2, const float* __restrict__ W3,
    const float* __restrict__ W4, const float* __restrict__ W5, const float* __restrict__ W8,
    float* __restrict__ W8T,
    unsigned short* __restrict__ W1h,  unsigned short* __restrict__ W1l,
    unsigned short* __restrict__ W2h,  unsigned short* __restrict__ W2l,
    unsigned short* __restrict__ W3dh, unsigned short* __restrict__ W3dl,
    unsigned short* __restrict__ W3qh, unsigned short* __restrict__ W3ql,
    unsigned short* __restrict__ W4h,  unsigned short* __restrict__ W4l,
    unsigned short* __restrict__ W5dh, unsigned short* __restrict__ W5dl,
    unsigned short* __restrict__ W5qh, unsigned short* __restrict__ W5ql)
{
  const int t = blockIdx.x*256 + threadIdx.x;
  const int stride = gridDim.x*256;
  for (int i=t; i<128*1024; i+=stride){ int o=i>>10, c=i&1023; W8T[c*128+o]=W8[i]; }
  // W1: [64][14] zero-padded to [64][32], split
  for (int i=t; i<64*32; i+=stride){
    int o=i>>5, c=i&31;
    float f = (c < 14) ? W1[o*14 + c] : 0.f;
    unsigned u = __float_as_uint(f);
    W1h[i] = (unsigned short)(u >> 16);
    float lo = f - __uint_as_float(u & 0xffff0000u);
    W1l[i] = (unsigned short)(__float_as_uint(lo) >> 16);
  }
  for (int i=t; i<64*64; i+=stride){
    float f = W2[i];
    unsigned u = __float_as_uint(f);
    W2h[i] = (unsigned short)(u >> 16);
    float lo = f - __uint_as_float(u & 0xffff0000u);
    W2l[i] = (unsigned short)(__float_as_uint(lo) >> 16);
  }
  for (int i=t; i<64*64; i+=stride){
    int o=i>>6, c=i&63;
    float f = W3[o*128 + c];
    unsigned u = __float_as_uint(f);
    W3dh[i] = (unsigned short)(u >> 16);
    float lo = f - __uint_as_float(u & 0xffff0000u);
    W3dl[i] = (unsigned short)(__float_as_uint(lo) >> 16);
  }
  for (int i=t; i<64*64; i+=stride){
    int o=i>>6, c=i&63;
    float f = W3[o*128 + 64 + c];
    unsigned u = __float_as_uint(f);
    W3qh[i] = (unsigned short)(u >> 16);
    float lo = f - __uint_as_float(u & 0xffff0000u);
    W3ql[i] = (unsigned short)(__float_as_uint(lo) >> 16);
  }
  for (int i=t; i<64*64; i+=stride){
    float f = W4[i];
    unsigned u = __float_as_uint(f);
    W4h[i] = (unsigned short)(u >> 16);
    float lo = f - __uint_as_float(u & 0xffff0000u);
    W4l[i] = (unsigned short)(__float_as_uint(lo) >> 16);
  }
  for (int i=t; i<64*64; i+=stride){
    int o=i>>6, c=i&63;
    float f = W5[o*128 + c];
    unsigned u = __float_as_uint(f);
    W5dh[i] = (unsigned short)(u >> 16);
    float lo = f - __uint_as_float(u & 0xffff0000u);
    W5dl[i] = (unsigned short)(__float_as_uint(lo) >> 16);
  }
  for (int i=t; i<64*64; i+=stride){
    int o=i>>6, c=i&63;
    float f = W5[o*128 + 64 + c];
    unsigned u = __float_as_uint(f);
    W5qh[i] = (unsigned short)(u >> 16);
    float lo = f - __uint_as_float(u & 0xffff0000u);
    W5ql[i] = (unsigned short)(__float_as_uint(lo) >> 16);
  }
}

// ---------------- one-time fp32 -> split bf16 (hi/lo) + squared norms ----------------
__global__ __launch_bounds__(256) void cvt_k(const float* __restrict__ xin,
    unsigned short* __restrict__ Xh, unsigned short* __restrict__ Xl, float* __restrict__ xx)
{
  const int gid = blockIdx.x*256 + threadIdx.x;   // BB*NN*8 threads
  const int p = gid >> 3, c8 = (gid & 7) << 3;
  const float* src = xin + (size_t)p*64 + c8;
  float fv[8];
  *(float4*)&fv[0] = *(const float4*)(src);
  *(float4*)&fv[4] = *(const float4*)(src + 4);
  unsigned hp[4], lp[4];
  float ssq = 0.f;
  #pragma unroll
  for (int e=0; e<4; e++){
    float f0 = fv[2*e], f1 = fv[2*e+1];
    ssq += f0*f0 + f1*f1;
    unsigned u0 = __float_as_uint(f0), u1 = __float_as_uint(f1);
    hp[e] = (u0 >> 16) | (u1 & 0xffff0000u);
    float l0 = f0 - __uint_as_float(u0 & 0xffff0000u);
    float l1 = f1 - __uint_as_float(u1 & 0xffff0000u);
    lp[e] = (__float_as_uint(l0) >> 16) | (__float_as_uint(l1) & 0xffff0000u);
  }
  *(uint4*)(Xh + (size_t)p*64 + c8) = uint4{hp[0],hp[1],hp[2],hp[3]};
  *(uint4*)(Xl + (size_t)p*64 + c8) = uint4{lp[0],lp[1],lp[2],lp[3]};
  ssq += __shfl_xor(ssq, 1, 64);
  ssq += __shfl_xor(ssq, 2, 64);
  ssq += __shfl_xor(ssq, 4, 64);
  if ((gid & 7) == 0) xx[p] = ssq;
}

// ---------------- knn over first 2 channels: two-phase selection ----------------
__global__ __launch_bounds__(256) void knn2d_k(const float* __restrict__ x, u64* __restrict__ pk)
{
  __shared__ float px[1024], py[1024], pxx[1024];
  __shared__ unsigned cnt[64];
  __shared__ u64 lst[CAP][64];
  const int tid = threadIdx.x;
  const int b  = blockIdx.x >> 8;
  const int qt = (blockIdx.x >> 2) & 63;
  const int h  = blockIdx.x & 3;
  const int q0 = qt*64;
  const int m0g = h*1024;
  const float* xb = x + (size_t)b*7*NN;
  for (int m = tid; m < 1024; m += 256){
    float a = xb[m0g + m], c = xb[NN + m0g + m];
    px[m] = a; py[m] = c; pxx[m] = a*a + c*c;
  }
  if (tid < 64) cnt[tid] = 0;
  __syncthreads();

  const int ty = tid >> 4, tx = tid & 15;
  const int qr = ty*4;
  float qx4[4], qy4[4], q24[4];
  #pragma unroll
  for (int i=0;i<4;i++){
    float a = xb[q0+qr+i], c = xb[NN + q0+qr+i];
    qx4[i] = a; qy4[i] = c; q24[i] = a*a + c*c;
  }

  float bv[4][TT];
  #pragma unroll
  for (int i=0;i<4;i++){
    #pragma unroll
    for (int s=0;s<TT;s++) bv[i][s] = -__builtin_inff();
  }

  for (int ot=0; ot<8; ot++){
    #pragma unroll
    for (int j=0;j<8;j++){
      const int ml = ot*128 + j*16 + tx;
      const float cmx = px[ml], cmy = py[ml], cm2 = pxx[ml];
      #pragma unroll
      for (int i=0;i<4;i++){
        float dot = qx4[i]*cmx + qy4[i]*cmy;
        float v = (-q24[i]) - (-2.f*dot) - cm2;
        float c = v;
        #pragma unroll
        for (int s=0;s<TT;s++){
          float nb = fmaxf(bv[i][s], c);
          c = fminf(bv[i][s], c);
          bv[i][s] = nb;
        }
      }
    }
  }

  float thr[4];
  #pragma unroll
  for (int i=0;i<4;i++){
    float m = 0.f;
    #pragma unroll
    for (int k=0;k<10;k++){
      float hh = bv[i][0];
      m = hh;
      m = fmaxf(m, __shfl_xor(m, 1, 64));
      m = fmaxf(m, __shfl_xor(m, 2, 64));
      m = fmaxf(m, __shfl_xor(m, 4, 64));
      m = fmaxf(m, __shfl_xor(m, 8, 64));
      if (k < 9){
        if (hh == m){
          #pragma unroll
          for (int s=0;s<TT-1;s++) bv[i][s] = bv[i][s+1];
          bv[i][TT-1] = -__builtin_inff();
        }
      }
    }
    thr[i] = m;
  }

  for (int ot=0; ot<8; ot++){
    #pragma unroll
    for (int j=0;j<8;j++){
      const int ml = ot*128 + j*16 + tx;
      const float cmx = px[ml], cmy = py[ml], cm2 = pxx[ml];
      const unsigned mk = ~(unsigned)(m0g + ml);
      #pragma unroll
      for (int i=0;i<4;i++){
        float dot = qx4[i]*cmx + qy4[i]*cmy;
        float v = (-q24[i]) - (-2.f*dot) - cm2;
        if (v >= thr[i]){
          u64 key = ((u64)fenc(v) << 32) | mk;
          const int r = qr + i;
          unsigned slot = atomicAdd(&cnt[r], 1u);
          if (slot < CAP) lst[slot][r] = key;
        }
      }
    }
  }
  __syncthreads();

  if (tid < 64){
    int n = (int)cnt[tid]; if (n > CAP) n = CAP;
    u64* op = pk + (((size_t)b*NN + q0 + tid)*4 + h)*KK;
    for (int k=0;k<KK;k++){
      u64 best = 0ull; int bi = 0;
      for (int s=0;s<n;s++){
        u64 v2 = lst[s][tid];
        if (v2 > best){ best = v2; bi = s; }
      }
      if (best) lst[bi][tid] = 0ull;
      op[k] = best;
    }
  }
}

// ---------------- knn over 64 channels: two-phase selection (top-TT network) --------
__global__ __launch_bounds__(256) void knn64_k(const unsigned short* __restrict__ Xh,
    const unsigned short* __restrict__ Xl, const float* __restrict__ xx, u64* __restrict__ pk)
{
  __shared__ unsigned short Ch[64*72], Cl[64*72];
  __shared__ float cxx[64];
  __shared__ unsigned cnt[64];
  __shared__ u64 lst[CAP][64];
  const int tid = threadIdx.x;
  const int b  = blockIdx.x >> 8;
  const int qt = (blockIdx.x >> 2) & 63;
  const int h  = blockIdx.x & 3;
  const int q0 = qt*64;
  const int m0g = h*1024;
  const unsigned short* Xhb = Xh + (size_t)b*NN*64;
  const unsigned short* Xlb = Xl + (size_t)b*NN*64;
  const float* xxb = xx + (size_t)b*NN;

  const int sp = tid >> 2;
  const int sc = (tid & 3) << 4;

  const int lane = tid & 63;
  const int w    = tid >> 6;
  const int col  = lane & 15;
  const int quad = (tid >> 4) & 3;
  const int qr   = (tid >> 4)*4;

  const size_t abase = (size_t)(q0 + w*16 + col)*64 + quad*8;
  bf16x8 Ah0 = *(const bf16x8*)(Xhb + abase);
  bf16x8 Ah1 = *(const bf16x8*)(Xhb + abase + 32);
  bf16x8 Al0 = *(const bf16x8*)(Xlb + abase);
  bf16x8 Al1 = *(const bf16x8*)(Xlb + abase + 32);

  float qx4[4];
  #pragma unroll
  for (int i=0;i<4;i++) qx4[i] = xxb[q0 + qr + i];

  if (tid < 64) cnt[tid] = 0;

  float bv[4][TT];
  #pragma unroll
  for (int i=0;i<4;i++){
    #pragma unroll
    for (int s=0;s<TT;s++) bv[i][s] = -__builtin_inff();
  }

  for (int ct=0; ct<16; ct++){
    const int m0 = m0g + ct*64;
    __syncthreads();
    {
      const uint4* sh = (const uint4*)(Xhb + (size_t)(m0+sp)*64 + sc);
      const uint4* sl = (const uint4*)(Xlb + (size_t)(m0+sp)*64 + sc);
      uint4 h0 = sh[0], h1 = sh[1], l0 = sl[0], l1 = sl[1];
      *(uint4*)(&Ch[sp*72 + sc])     = h0;
      *(uint4*)(&Ch[sp*72 + sc + 8]) = h1;
      *(uint4*)(&Cl[sp*72 + sc])     = l0;
      *(uint4*)(&Cl[sp*72 + sc + 8]) = l1;
      if (tid < 64) cxx[tid] = xxb[m0 + tid];
    }
    __syncthreads();

    #pragma unroll
    for (int j=0;j<4;j++){
      const int boff = (j*16 + col)*72 + quad*8;
      bf16x8 Bh0 = *(const bf16x8*)(&Ch[boff]);
      bf16x8 Bh1 = *(const bf16x8*)(&Ch[boff+32]);
      bf16x8 Bl0 = *(const bf16x8*)(&Cl[boff]);
      bf16x8 Bl1 = *(const bf16x8*)(&Cl[boff+32]);
      f32x4 d = {0.f,0.f,0.f,0.f};
      d = __builtin_amdgcn_mfma_f32_16x16x32_bf16(Al0, Bh0, d, 0,0,0);
      d = __builtin_amdgcn_mfma_f32_16x16x32_bf16(Ah0, Bl0, d, 0,0,0);
      d = __builtin_amdgcn_mfma_f32_16x16x32_bf16(Ah0, Bh0, d, 0,0,0);
      d = __builtin_amdgcn_mfma_f32_16x16x32_bf16(Al1, Bh1, d, 0,0,0);
      d = __builtin_amdgcn_mfma_f32_16x16x32_bf16(Ah1, Bl1, d, 0,0,0);
      d = __builtin_amdgcn_mfma_f32_16x16x32_bf16(Ah1, Bh1, d, 0,0,0);

      const float cx = cxx[j*16 + col];
      #pragma unroll
      for (int i=0;i<4;i++){
        float v = (-qx4[i]) - (-2.f*d[i]) - cx;
        float c = v;
        #pragma unroll
        for (int s=0;s<TT;s++){
          float nb = fmaxf(bv[i][s], c);
          c = fminf(bv[i][s], c);
          bv[i][s] = nb;
        }
      }
    }
  }

  float thr[4];
  #pragma unroll
  for (int i=0;i<4;i++){
    float m = 0.f;
    #pragma unroll
    for (int k=0;k<10;k++){
      float hh = bv[i][0];
      m = hh;
      m = fmaxf(m, __shfl_xor(m, 1, 64));
      m = fmaxf(m, __shfl_xor(m, 2, 64));
      m = fmaxf(m, __shfl_xor(m, 4, 64));
      m = fmaxf(m, __shfl_xor(m, 8, 64));
      if (k < 9){
        if (hh == m){
          #pragma unroll
          for (int s=0;s<TT-1;s++) bv[i][s] = bv[i][s+1];
          bv[i][TT-1] = -__builtin_inff();
        }
      }
    }
    thr[i] = m;
  }

  for (int ct=0; ct<16; ct++){
    const int m0 = m0g + ct*64;
    __syncthreads();
    {
      const uint4* sh = (const uint4*)(Xhb + (size_t)(m0+sp)*64 + sc);
      const uint4* sl = (const uint4*)(Xlb + (size_t)(m0+sp)*64 + sc);
      uint4 h0 = sh[0], h1 = sh[1], l0 = sl[0], l1 = sl[1];
      *(uint4*)(&Ch[sp*72 + sc])     = h0;
      *(uint4*)(&Ch[sp*72 + sc + 8]) = h1;
      *(uint4*)(&Cl[sp*72 + sc])     = l0;
      *(uint4*)(&Cl[sp*72 + sc + 8]) = l1;
      if (tid < 64) cxx[tid] = xxb[m0 + tid];
    }
    __syncthreads();

    #pragma unroll
    for (int j=0;j<4;j++){
      const int boff = (j*16 + col)*72 + quad*8;
      bf16x8 Bh0 = *(const bf16x8*)(&Ch[boff]);
      bf16x8 Bh1 = *(const bf16x8*)(&Ch[boff+32]);
      bf16x8 Bl0 = *(const bf16x8*)(&Cl[boff]);
      bf16x8 Bl1 = *(const bf16x8*)(&Cl[boff+32]);
      f32x4 d = {0.f,0.f,0.f,0.f};
      d = __builtin_amdgcn_mfma_f32_16x16x32_bf16(Al0, Bh0, d, 0,0,0);
      d = __builtin_amdgcn_mfma_f32_16x16x32_bf16(Ah0, Bl0, d, 0,0,0);
      d = __builtin_amdgcn_mfma_f32_16x16x32_bf16(Ah0, Bh0, d, 0,0,0);
      d = __builtin_amdgcn_mfma_f32_16x16x32_bf16(Al1, Bh1, d, 0,0,0);
      d = __builtin_amdgcn_mfma_f32_16x16x32_bf16(Ah1, Bl1, d, 0,0,0);
      d = __builtin_amdgcn_mfma_f32_16x16x32_bf16(Ah1, Bh1, d, 0,0,0);

      const int m = m0 + j*16 + col;
      const float cx = cxx[j*16 + col];
      const unsigned mk = ~(unsigned)m;
      #pragma unroll
      for (int i=0;i<4;i++){
        float v = (-qx4[i]) - (-2.f*d[i]) - cx;
        if (v >= thr[i]){
          u64 key = ((u64)fenc(v) << 32) | mk;
          const int r = qr + i;
          unsigned slot = atomicAdd(&cnt[r], 1u);
          if (slot < CAP) lst[slot][r] = key;
        }
      }
    }
  }
  __syncthreads();

  if (tid < 64){
    int n = (int)cnt[tid]; if (n > CAP) n = CAP;
    u64* op = pk + (((size_t)b*NN + q0 + tid)*4 + h)*KK;
    for (int k=0;k<KK;k++){
      u64 best = 0ull; int bi = 0;
      for (int s=0;s<n;s++){
        u64 v2 = lst[s][tid];
        if (v2 > best){ best = v2; bi = s; }
      }
      if (best) lst[bi][tid] = 0ull;
      op[k] = best;
    }
  }
}

// ---------------- merge four sorted-desc 10-key quarters -> final idx ----------------
__global__ __launch_bounds__(256) void kmerge_k(const u64* __restrict__ pk, int* __restrict__ idxo)
{
  const int q = blockIdx.x*256 + threadIdx.x;   // q < BB*NN
  const u64* A = pk + (size_t)q*(4*KK);
  int* op = idxo + (size_t)q*KK;
  int ia = 0, ib = 0, ic = 0, id = 0;
  #pragma unroll
  for (int k=0;k<KK;k++){
    u64 a  = (ia < KK) ? A[ia]        : 0ull;
    u64 b2 = (ib < KK) ? A[KK + ib]   : 0ull;
    u64 c2 = (ic < KK) ? A[2*KK + ic] : 0ull;
    u64 d2 = (id < KK) ? A[3*KK + id] : 0ull;
    u64 m1 = a >= b2 ? a : b2;  int s1 = a >= b2 ? 0 : 1;
    u64 m2 = c2 >= d2 ? c2 : d2; int s2 = c2 >= d2 ? 2 : 3;
    u64 mm = m1 >= m2 ? m1 : m2; int ss = m1 >= m2 ? s1 : s2;
    op[k] = (int)(~(unsigned)mm);
    if (ss == 0) ia++; else if (ss == 1) ib++; else if (ss == 2) ic++; else id++;
  }
}

// ---------------- edge conv 1: MFMA split-bf16 (GEMM1: W1@feat K=32; GEMM2: W2@z1) ---
// feat col (p,j) = [xg0-xq0, xg1-xq1, xg2..xg6, xq0..xq6, 0,0] (14 dims pad 32).
// Query terms are inside the column -> no separate Q GEMM / bpermute needed.
// GEMM2 + epilogue identical to the twice-verified edge2 pattern.
__global__ __launch_bounds__(256) void edge1_k(const float* __restrict__ x, const int* __restrict__ idx,
    const unsigned short* __restrict__ W1h, const unsigned short* __restrict__ W1l,
    const unsigned short* __restrict__ W2h, const unsigned short* __restrict__ W2l,
    const float* __restrict__ s1, const float* __restrict__ t1,
    const float* __restrict__ s2, const float* __restrict__ t2,
    float* __restrict__ x1t)
{
  __shared__ unsigned short Fh[80*36], Fl[80*36];   // GEMM1 B: 80 cols x K=32 (pad 36)
  __shared__ unsigned short Zh[80*72], Zl[80*72];   // z1 overlay for GEMM2
  __shared__ float accf[64*8];
  const int tid = threadIdx.x;
  const size_t p0 = (size_t)blockIdx.x * 8;

  ((float2*)accf)[tid] = float2{0.f, 0.f};

  if (tid < 80){
    const int p = tid/10, j = tid - p*10;
    const size_t pt = p0 + p;
    const int bb = (int)(pt >> 12);
    const int n = (int)(pt & 4095);
    const int ij = idx[pt*KK + j];
    const float* xb = x + (size_t)bb*7*NN;
    float f[16];
    const float q0v = xb[n], q1v = xb[NN + n];
    f[0] = xb[ij] - q0v;
    f[1] = xb[NN + ij] - q1v;
    #pragma unroll
    for (int c=2;c<7;c++) f[c] = xb[c*NN + ij];
    f[7] = q0v; f[8] = q1v;
    #pragma unroll
    for (int c=2;c<7;c++) f[7+c] = xb[c*NN + n];
    f[14] = 0.f; f[15] = 0.f;
    unsigned hp[8], lp[8];
    #pragma unroll
    for (int e=0;e<8;e++){
      float a0 = f[2*e], a1 = f[2*e+1];
      unsigned u0 = __float_as_uint(a0), u1 = __float_as_uint(a1);
      hp[e] = (u0 >> 16) | (u1 & 0xffff0000u);
      float l0 = a0 - __uint_as_float(u0 & 0xffff0000u);
      float l1 = a1 - __uint_as_float(u1 & 0xffff0000u);
      lp[e] = (__float_as_uint(l0) >> 16) | (__float_as_uint(l1) & 0xffff0000u);
    }
    const uint4 z{0u,0u,0u,0u};
    *(uint4*)(&Fh[tid*36])      = uint4{hp[0],hp[1],hp[2],hp[3]};
    *(uint4*)(&Fh[tid*36 + 8])  = uint4{hp[4],hp[5],hp[6],hp[7]};
    *(uint4*)(&Fh[tid*36 + 16]) = z;
    *(uint4*)(&Fh[tid*36 + 24]) = z;
    *(uint4*)(&Fl[tid*36])      = uint4{lp[0],lp[1],lp[2],lp[3]};
    *(uint4*)(&Fl[tid*36 + 8])  = uint4{lp[4],lp[5],lp[6],lp[7]};
    *(uint4*)(&Fl[tid*36 + 16]) = z;
    *(uint4*)(&Fl[tid*36 + 24]) = z;
  }
  __syncthreads();

  const int lane = tid & 63;
  const int w    = tid >> 6;
  const int colL = lane & 15;
  const int quad = lane >> 4;

  // ---- GEMM1: y1 = W1 @ feat (K=32, 3 split MFMAs per tile) ----
  const int arow1 = (w*16 + colL)*32 + quad*8;
  bf16x8 A1h = *(const bf16x8*)(W1h + arow1);
  bf16x8 A1l = *(const bf16x8*)(W1l + arow1);

  f32x4 C1[5];
  #pragma unroll
  for (int t=0;t<5;t++){
    const int boff = (t*16 + colL)*36 + quad*8;
    bf16x8 Bh = *(const bf16x8*)(&Fh[boff]);
    bf16x8 Bl = *(const bf16x8*)(&Fl[boff]);
    f32x4 d = {0.f,0.f,0.f,0.f};
    d = __builtin_amdgcn_mfma_f32_16x16x32_bf16(A1l, Bh, d, 0,0,0);
    d = __builtin_amdgcn_mfma_f32_16x16x32_bf16(A1h, Bl, d, 0,0,0);
    d = __builtin_amdgcn_mfma_f32_16x16x32_bf16(A1h, Bh, d, 0,0,0);
    C1[t] = d;
  }

  float s1v[4], t1v[4], s2v[4], t2v[4];
  #pragma unroll
  for (int i=0;i<4;i++){
    const int o = w*16 + quad*4 + i;
    s1v[i]=s1[o]; t1v[i]=t1[o]; s2v[i]=s2[o]; t2v[i]=t2[o];
  }

  // ---- z1 = lrelu(C1*s1 + t1), split-bf16, into Zh/Zl (no sync needed: new bufs) ----
  #pragma unroll
  for (int t=0;t<5;t++){
    const int gc = t*16 + colL;
    float z[4];
    #pragma unroll
    for (int i=0;i<4;i++){
      float zp = C1[t][i]*s1v[i] + t1v[i];
      z[i] = zp >= 0.f ? zp : 0.2f*zp;
    }
    unsigned u0=__float_as_uint(z[0]), u1=__float_as_uint(z[1]);
    unsigned u2=__float_as_uint(z[2]), u3=__float_as_uint(z[3]);
    unsigned h01 = (u0>>16) | (u1 & 0xffff0000u);
    unsigned h23 = (u2>>16) | (u3 & 0xffff0000u);
    float l0 = z[0]-__uint_as_float(u0&0xffff0000u);
    float l1 = z[1]-__uint_as_float(u1&0xffff0000u);
    float l2 = z[2]-__uint_as_float(u2&0xffff0000u);
    float l3 = z[3]-__uint_as_float(u3&0xffff0000u);
    unsigned l01 = (__float_as_uint(l0)>>16) | (__float_as_uint(l1)&0xffff0000u);
    unsigned l23 = (__float_as_uint(l2)>>16) | (__float_as_uint(l3)&0xffff0000u);
    const int rb = w*16 + quad*4;
    *(uint2*)(&Zh[gc*72 + rb]) = uint2{h01,h23};
    *(uint2*)(&Zl[gc*72 + rb]) = uint2{l01,l23};
  }
  __syncthreads();

  // ---- GEMM2: W2 @ z1, lrelu, mean-accumulate (edge2-verified pattern) ----
  const int arow = (w*16 + colL)*64 + quad*8;
  bf16x8 A2h0 = *(const bf16x8*)(W2h + arow);
  bf16x8 A2h1 = *(const bf16x8*)(W2h + arow + 32);
  bf16x8 A2l0 = *(const bf16x8*)(W2l + arow);
  bf16x8 A2l1 = *(const bf16x8*)(W2l + arow + 32);
  #pragma unroll
  for (int t=0;t<5;t++){
    const int boff = (t*16 + colL)*72 + quad*8;
    bf16x8 Bh0 = *(const bf16x8*)(&Zh[boff]);
    bf16x8 Bh1 = *(const bf16x8*)(&Zh[boff+32]);
    bf16x8 Bl0 = *(const bf16x8*)(&Zl[boff]);
    bf16x8 Bl1 = *(const bf16x8*)(&Zl[boff+32]);
    f32x4 d = {0.f,0.f,0.f,0.f};
    d = __builtin_amdgcn_mfma_f32_16x16x32_bf16(A2l0, Bh0, d, 0,0,0);
    d = __builtin_amdgcn_mfma_f32_16x16x32_bf16(A2h0, Bl0, d, 0,0,0);
    d = __builtin_amdgcn_mfma_f32_16x16x32_bf16(A2h0, Bh0, d, 0,0,0);
    d = __builtin_amdgcn_mfma_f32_16x16x32_bf16(A2l1, Bh1, d, 0,0,0);
    d = __builtin_amdgcn_mfma_f32_16x16x32_bf16(A2h1, Bl1, d, 0,0,0);
    d = __builtin_amdgcn_mfma_f32_16x16x32_bf16(A2h1, Bh1, d, 0,0,0);
    const int gc = t*16 + colL;
    const int p  = gc/10;
    #pragma unroll
    for (int i=0;i<4;i++){
      float v = d[i]*s2v[i] + t2v[i];
      v = v >= 0.f ? v : 0.2f*v;
      atomicAdd(&accf[(w*16 + quad*4 + i)*8 + p], v);
    }
  }
  __syncthreads();

  {
    const int o = tid & 63;
    #pragma unroll
    for (int g=0; g<2; ++g){
      const int p = (tid>>6) + g*4;
      x1t[(p0+p)*64 + o] = accf[o*8+p] / 10.f;
    }
  }
}

// ---------------- edge conv 2: MFMA split-bf16 (GEMM1: W3d@d + W3q@xq, GEMM2: W4@z3) --
__global__ __launch_bounds__(256) void edge2_k(const float* __restrict__ x1t, const int* __restrict__ idx,
    const unsigned short* __restrict__ W3dh, const unsigned short* __restrict__ W3dl,
    const unsigned short* __restrict__ W3qh, const unsigned short* __restrict__ W3ql,
    const unsigned short* __restrict__ W4h,  const unsigned short* __restrict__ W4l,
    const float* __restrict__ s3, const float* __restrict__ t3,
    const float* __restrict__ s4, const float* __restrict__ t4,
    float* __restrict__ xout)
{
  __shared__ unsigned short Zh[80*72], Zl[80*72];   // D staging -> z3 overlay
  __shared__ unsigned short Qh[16*72], Ql[16*72];
  __shared__ float accf[64*8];
  const int tid = threadIdx.x;
  const size_t p0 = (size_t)blockIdx.x * 8;

  ((float2*)accf)[tid] = float2{0.f, 0.f};

  #pragma unroll
  for (int pass=0; pass<2; ++pass){
    const int col = pass*64 + (tid>>2);
    const int sc16 = (tid&3)*16;
    if (col < 88){
      float dv[16];
      if (col < 80){
        const int p = col/10, j = col - p*10;
        const size_t pt = p0 + p;
        const int bb = (int)(pt >> 12);
        const int ij = idx[pt*KK + j];
        const float* gs = x1t + ((size_t)bb*NN + ij)*64 + sc16;
        const float* qs = x1t + pt*64 + sc16;
        #pragma unroll
        for (int e=0;e<4;e++){
          float4 g4 = *(const float4*)(gs + e*4);
          float4 q4 = *(const float4*)(qs + e*4);
          dv[e*4+0]=g4.x-q4.x; dv[e*4+1]=g4.y-q4.y; dv[e*4+2]=g4.z-q4.z; dv[e*4+3]=g4.w-q4.w;
        }
      } else {
        const int cl = col - 80;
        const float* qs = x1t + (size_t)(p0+cl)*64 + sc16;
        #pragma unroll
        for (int e=0;e<4;e++){
          float4 q4 = *(const float4*)(qs + e*4);
          dv[e*4+0]=q4.x; dv[e*4+1]=q4.y; dv[e*4+2]=q4.z; dv[e*4+3]=q4.w;
        }
      }
      unsigned hp[8], lp[8];
      #pragma unroll
      for (int e=0;e<8;e++){
        float f0 = dv[2*e], f1 = dv[2*e+1];
        unsigned u0 = __float_as_uint(f0), u1 = __float_as_uint(f1);
        hp[e] = (u0 >> 16) | (u1 & 0xffff0000u);
        float l0 = f0 - __uint_as_float(u0 & 0xffff0000u);
        float l1 = f1 - __uint_as_float(u1 & 0xffff0000u);
        lp[e] = (__float_as_uint(l0) >> 16) | (__float_as_uint(l1) & 0xffff0000u);
      }
      if (col < 80){
        *(uint4*)(&Zh[col*72 + sc16])     = uint4{hp[0],hp[1],hp[2],hp[3]};
        *(uint4*)(&Zh[col*72 + sc16 + 8]) = uint4{hp[4],hp[5],hp[6],hp[7]};
        *(uint4*)(&Zl[col*72 + sc16])     = uint4{lp[0],lp[1],lp[2],lp[3]};
        *(uint4*)(&Zl[col*72 + sc16 + 8]) = uint4{lp[4],lp[5],lp[6],lp[7]};
      } else {
        const int cl = col - 80;
        *(uint4*)(&Qh[cl*72 + sc16])     = uint4{hp[0],hp[1],hp[2],hp[3]};
        *(uint4*)(&Qh[cl*72 + sc16 + 8]) = uint4{hp[4],hp[5],hp[6],hp[7]};
        *(uint4*)(&Ql[cl*72 + sc16])     = uint4{lp[0],lp[1],lp[2],lp[3]};
        *(uint4*)(&Ql[cl*72 + sc16 + 8]) = uint4{lp[4],lp[5],lp[6],lp[7]};
      }
    } else if (col < 96){
      const int cl = col - 80;
      const uint4 z{0u,0u,0u,0u};
      *(uint4*)(&Qh[cl*72 + sc16])     = z;
      *(uint4*)(&Qh[cl*72 + sc16 + 8]) = z;
      *(uint4*)(&Ql[cl*72 + sc16])     = z;
      *(uint4*)(&Ql[cl*72 + sc16 + 8]) = z;
    }
  }
  __syncthreads();

  const int lane = tid & 63;
  const int w    = tid >> 6;
  const int colL = lane & 15;
  const int quad = lane >> 4;
  const int arow = (w*16 + colL)*64 + quad*8;

  bf16x8 Adh0 = *(const bf16x8*)(W3dh + arow);
  bf16x8 Adh1 = *(const bf16x8*)(W3dh + arow + 32);
  bf16x8 Adl0 = *(const bf16x8*)(W3dl + arow);
  bf16x8 Adl1 = *(const bf16x8*)(W3dl + arow + 32);

  f32x4 C1[5];
  #pragma unroll
  for (int t=0;t<5;t++){
    const int boff = (t*16 + colL)*72 + quad*8;
    bf16x8 Bh0 = *(const bf16x8*)(&Zh[boff]);
    bf16x8 Bh1 = *(const bf16x8*)(&Zh[boff+32]);
    bf16x8 Bl0 = *(const bf16x8*)(&Zl[boff]);
    bf16x8 Bl1 = *(const bf16x8*)(&Zl[boff+32]);
    f32x4 d = {0.f,0.f,0.f,0.f};
    d = __builtin_amdgcn_mfma_f32_16x16x32_bf16(Adl0, Bh0, d, 0,0,0);
    d = __builtin_amdgcn_mfma_f32_16x16x32_bf16(Adh0, Bl0, d, 0,0,0);
    d = __builtin_amdgcn_mfma_f32_16x16x32_bf16(Adh0, Bh0, d, 0,0,0);
    d = __builtin_amdgcn_mfma_f32_16x16x32_bf16(Adl1, Bh1, d, 0,0,0);
    d = __builtin_amdgcn_mfma_f32_16x16x32_bf16(Adh1, Bl1, d, 0,0,0);
    d = __builtin_amdgcn_mfma_f32_16x16x32_bf16(Adh1, Bh1, d, 0,0,0);
    C1[t] = d;
  }
  f32x4 Cu;
  {
    bf16x8 Aqh0 = *(const bf16x8*)(W3qh + arow);
    bf16x8 Aqh1 = *(const bf16x8*)(W3qh + arow + 32);
    bf16x8 Aql0 = *(const bf16x8*)(W3ql + arow);
    bf16x8 Aql1 = *(const bf16x8*)(W3ql + arow + 32);
    const int boff = colL*72 + quad*8;
    bf16x8 Bh0 = *(const bf16x8*)(&Qh[boff]);
    bf16x8 Bh1 = *(const bf16x8*)(&Qh[boff+32]);
    bf16x8 Bl0 = *(const bf16x8*)(&Ql[boff]);
    bf16x8 Bl1 = *(const bf16x8*)(&Ql[boff+32]);
    f32x4 d = {0.f,0.f,0.f,0.f};
    d = __builtin_amdgcn_mfma_f32_16x16x32_bf16(Aql0, Bh0, d, 0,0,0);
    d = __builtin_amdgcn_mfma_f32_16x16x32_bf16(Aqh0, Bl0, d, 0,0,0);
    d = __builtin_amdgcn_mfma_f32_16x16x32_bf16(Aqh0, Bh0, d, 0,0,0);
    d = __builtin_amdgcn_mfma_f32_16x16x32_bf16(Aql1, Bh1, d, 0,0,0);
    d = __builtin_amdgcn_mfma_f32_16x16x32_bf16(Aqh1, Bl1, d, 0,0,0);
    d = __builtin_amdgcn_mfma_f32_16x16x32_bf16(Aqh1, Bh1, d, 0,0,0);
    Cu = d;
  }

  float s3v[4], t3v[4], s4v[4], t4v[4];
  #pragma unroll
  for (int i=0;i<4;i++){
    const int o = w*16 + quad*4 + i;
    s3v[i]=s3[o]; t3v[i]=t3[o]; s4v[i]=s4[o]; t4v[i]=t4[o];
  }

  __syncthreads();

  #pragma unroll
  for (int t=0;t<5;t++){
    const int gc = t*16 + colL;
    const int p  = gc/10;
    const int srcb = (((lane & 48) | p) << 2);
    float z[4];
    #pragma unroll
    for (int i=0;i<4;i++){
      float ui = __int_as_float(__builtin_amdgcn_ds_bpermute(srcb, __float_as_int(Cu[i])));
      float zp = (C1[t][i] + ui)*s3v[i] + t3v[i];
      z[i] = zp >= 0.f ? zp : 0.2f*zp;
    }
    unsigned u0=__float_as_uint(z[0]), u1=__float_as_uint(z[1]);
    unsigned u2=__float_as_uint(z[2]), u3=__float_as_uint(z[3]);
    unsigned h01 = (u0>>16) | (u1 & 0xffff0000u);
    unsigned h23 = (u2>>16) | (u3 & 0xffff0000u);
    float l0 = z[0]-__uint_as_float(u0&0xffff0000u);
    float l1 = z[1]-__uint_as_float(u1&0xffff0000u);
    float l2 = z[2]-__uint_as_float(u2&0xffff0000u);
    float l3 = z[3]-__uint_as_float(u3&0xffff0000u);
    unsigned l01 = (__float_as_uint(l0)>>16) | (__float_as_uint(l1)&0xffff0000u);
    unsigned l23 = (__float_as_uint(l2)>>16) | (__float_as_uint(l3)&0xffff0000u);
    const int rb = w*16 + quad*4;
    *(uint2*)(&Zh[gc*72 + rb]) = uint2{h01,h23};
    *(uint2*)(&Zl[gc*72 + rb]) = uint2{l01,l23};
  }
  __syncthreads();

  bf16x8 A4h0 = *(const bf16x8*)(W4h + arow);
  bf16x8 A4h1 = *(const bf16x8*)(W4h + arow + 32);
  bf16x8 A4l0 = *(const bf16x8*)(W4l + arow);
  bf16x8 A4l1 = *(const bf16x8*)(W4l + arow + 32);
  #pragma unroll
  for (int t=0;t<5;t++){
    const int boff = (t*16 + colL)*72 + quad*8;
    bf16x8 Bh0 = *(const bf16x8*)(&Zh[boff]);
    bf16x8 Bh1 = *(const bf16x8*)(&Zh[boff+32]);
    bf16x8 Bl0 = *(const bf16x8*)(&Zl[boff]);
    bf16x8 Bl1 = *(const bf16x8*)(&Zl[boff+32]);
    f32x4 d = {0.f,0.f,0.f,0.f};
    d = __builtin_amdgcn_mfma_f32_16x16x32_bf16(A4l0, Bh0, d, 0,0,0);
    d = __builtin_amdgcn_mfma_f32_16x16x32_bf16(A4h0, Bl0, d, 0,0,0);
    d = __builtin_amdgcn_mfma_f32_16x16x32_bf16(A4h0, Bh0, d, 0,0,0);
    d = __builtin_amdgcn_mfma_f32_16x16x32_bf16(A4l1, Bh1, d, 0,0,0);
    d = __builtin_amdgcn_mfma_f32_16x16x32_bf16(A4h1, Bl1, d, 0,0,0);
    d = __builtin_amdgcn_mfma_f32_16x16x32_bf16(A4h1, Bh1, d, 0,0,0);
    const int gc = t*16 + colL;
    const int p  = gc/10;
    #pragma unroll
    for (int i=0;i<4;i++){
      float v = d[i]*s4v[i] + t4v[i];
      v = v >= 0.f ? v : 0.2f*v;
      atomicAdd(&accf[(w*16 + quad*4 + i)*8 + p], v);
    }
  }
  __syncthreads();

  {
    const int o = tid & 63;
    #pragma unroll
    for (int g=0; g<2; ++g){
      const int p = (tid>>6) + g*4;
      xout[(p0+p)*64 + o] = accf[o*8+p] / 10.f;
    }
  }
}

// ---------------- edge conv 3: MFMA split-bf16 (GEMM1 only: W5d@d + W5q@xq) ----------
__global__ __launch_bounds__(256) void edge3_k(const float* __restrict__ xin, const int* __restrict__ idx,
    const unsigned short* __restrict__ W5dh, const unsigned short* __restrict__ W5dl,
    const unsigned short* __restrict__ W5qh, const unsigned short* __restrict__ W5ql,
    const float* __restrict__ s5, const float* __restrict__ t5,
    float* __restrict__ xout)
{
  __shared__ unsigned short Zh[80*72], Zl[80*72];
  __shared__ unsigned short Qh[16*72], Ql[16*72];
  __shared__ float accf[64*8];
  const int tid = threadIdx.x;
  const size_t p0 = (size_t)blockIdx.x * 8;

  ((float2*)accf)[tid] = float2{0.f, 0.f};

  #pragma unroll
  for (int pass=0; pass<2; ++pass){
    const int col = pass*64 + (tid>>2);
    const int sc16 = (tid&3)*16;
    if (col < 88){
      float dv[16];
      if (col < 80){
        const int p = col/10, j = col - p*10;
        const size_t pt = p0 + p;
        const int bb = (int)(pt >> 12);
        const int ij = idx[pt*KK + j];
        const float* gs = xin + ((size_t)bb*NN + ij)*64 + sc16;
        const float* qs = xin + pt*64 + sc16;
        #pragma unroll
        for (int e=0;e<4;e++){
          float4 g4 = *(const float4*)(gs + e*4);
          float4 q4 = *(const float4*)(qs + e*4);
          dv[e*4+0]=g4.x-q4.x; dv[e*4+1]=g4.y-q4.y; dv[e*4+2]=g4.z-q4.z; dv[e*4+3]=g4.w-q4.w;
        }
      } else {
        const int cl = col - 80;
        const float* qs = xin + (size_t)(p0+cl)*64 + sc16;
        #pragma unroll
        for (int e=0;e<4;e++){
          float4 q4 = *(const float4*)(qs + e*4);
          dv[e*4+0]=q4.x; dv[e*4+1]=q4.y; dv[e*4+2]=q4.z; dv[e*4+3]=q4.w;
        }
      }
      unsigned hp[8], lp[8];
      #pragma unroll
      for (int e=0;e<8;e++){
        float f0 = dv[2*e], f1 = dv[2*e+1];
        unsigned u0 = __float_as_uint(f0), u1 = __float_as_uint(f1);
        hp[e] = (u0 >> 16) | (u1 & 0xffff0000u);
        float l0 = f0 - __uint_as_float(u0 & 0xffff0000u);
        float l1 = f1 - __uint_as_float(u1 & 0xffff0000u);
        lp[e] = (__float_as_uint(l0) >> 16) | (__float_as_uint(l1) & 0xffff0000u);
      }
      if (col < 80){
        *(uint4*)(&Zh[col*72 + sc16])     = uint4{hp[0],hp[1],hp[2],hp[3]};
        *(uint4*)(&Zh[col*72 + sc16 + 8]) = uint4{hp[4],hp[5],hp[6],hp[7]};
        *(uint4*)(&Zl[col*72 + sc16])     = uint4{lp[0],lp[1],lp[2],lp[3]};
        *(uint4*)(&Zl[col*72 + sc16 + 8]) = uint4{lp[4],lp[5],lp[6],lp[7]};
      } else {
        const int cl = col - 80;
        *(uint4*)(&Qh[cl*72 + sc16])     = uint4{hp[0],hp[1],hp[2],hp[3]};
        *(uint4*)(&Qh[cl*72 + sc16 + 8]) = uint4{hp[4],hp[5],hp[6],hp[7]};
        *(uint4*)(&Ql[cl*72 + sc16])     = uint4{lp[0],lp[1],lp[2],lp[3]};
        *(uint4*)(&Ql[cl*72 + sc16 + 8]) = uint4{lp[4],lp[5],lp[6],lp[7]};
      }
    } else if (col < 96){
      const int cl = col - 80;
      const uint4 z{0u,0u,0u,0u};
      *(uint4*)(&Qh[cl*72 + sc16])     = z;
      *(uint4*)(&Qh[cl*72 + sc16 + 8]) = z;
      *(uint4*)(&Ql[cl*72 + sc16])     = z;
      *(uint4*)(&Ql[cl*72 + sc16 + 8]) = z;
    }
  }
  __syncthreads();

  const int lane = tid & 63;
  const int w    = tid >> 6;
  const int colL = lane & 15;
  const int quad = lane >> 4;
  const int arow = (w*16 + colL)*64 + quad*8;

  bf16x8 Adh0 = *(const bf16x8*)(W5dh + arow);
  bf16x8 Adh1 = *(const bf16x8*)(W5dh + arow + 32);
  bf16x8 Adl0 = *(const bf16x8*)(W5dl + arow);
  bf16x8 Adl1 = *(const bf16x8*)(W5dl + arow + 32);

  f32x4 C1[5];
  #pragma unroll
  for (int t=0;t<5;t++){
    const int boff = (t*16 + colL)*72 + quad*8;
    bf16x8 Bh0 = *(const bf16x8*)(&Zh[boff]);
    bf16x8 Bh1 = *(const bf16x8*)(&Zh[boff+32]);
    bf16x8 Bl0 = *(const bf16x8*)(&Zl[boff]);
    bf16x8 Bl1 = *(const bf16x8*)(&Zl[boff+32]);
    f32x4 d = {0.f,0.f,0.f,0.f};
    d = __builtin_amdgcn_mfma_f32_16x16x32_bf16(Adl0, Bh0, d, 0,0,0);
    d = __builtin_amdgcn_mfma_f32_16x16x32_bf16(Adh0, Bl0, d, 0,0,0);
    d = __builtin_amdgcn_mfma_f32_16x16x32_bf16(Adh0, Bh0, d, 0,0,0);
    d = __builtin_amdgcn_mfma_f32_16x16x32_bf16(Adl1, Bh1, d, 0,0,0);
    d = __builtin_amdgcn_mfma_f32_16x16x32_bf16(Adh1, Bl1, d, 0,0,0);
    d = __builtin_amdgcn_mfma_f32_16x16x32_bf16(Adh1, Bh1, d, 0,0,0);
    C1[t] = d;
  }
  f32x4 Cu;
  {
    bf16x8 Aqh0 = *(const bf16x8*)(W5qh + arow);
    bf16x8 Aqh1 = *(const bf16x8*)(W5qh + arow + 32);
    bf16x8 Aql0 = *(const bf16x8*)(W5ql + arow);
    bf16x8 Aql1 = *(const bf16x8*)(W5ql + arow + 32);
    const int boff = colL*72 + quad*8;
    bf16x8 Bh0 = *(const bf16x8*)(&Qh[boff]);
    bf16x8 Bh1 = *(const bf16x8*)(&Qh[boff+32]);
    bf16x8 Bl0 = *(const bf16x8*)(&Ql[boff]);
    bf16x8 Bl1 = *(const bf16x8*)(&Ql[boff+32]);
    f32x4 d = {0.f,0.f,0.f,0.f};
    d = __builtin_amdgcn_mfma_f32_16x16x32_bf16(Aql0, Bh0, d, 0,0,0);
    d = __builtin_amdgcn_mfma_f32_16x16x32_bf16(Aqh0, Bl0, d, 0,0,0);
    d = __builtin_amdgcn_mfma_f32_16x16x32_bf16(Aqh0, Bh0, d, 0,0,0);
    d = __builtin_amdgcn_mfma_f32_16x16x32_bf16(Aql1, Bh1, d, 0,0,0);
    d = __builtin_amdgcn_mfma_f32_16x16x32_bf16(Aqh1, Bl1, d, 0,0,0);
    d = __builtin_amdgcn_mfma_f32_16x16x32_bf16(Aqh1, Bh1, d, 0,0,0);
    Cu = d;
  }

  float s5v[4], t5v[4];
  #pragma unroll
  for (int i=0;i<4;i++){
    const int o = w*16 + quad*4 + i;
    s5v[i]=s5[o]; t5v[i]=t5[o];
  }

  #pragma unroll
  for (int t=0;t<5;t++){
    const int gc = t*16 + colL;
    const int p  = gc/10;
    const int srcb = (((lane & 48) | p) << 2);
    #pragma unroll
    for (int i=0;i<4;i++){
      float ui = __int_as_float(__builtin_amdgcn_ds_bpermute(srcb, __float_as_int(Cu[i])));
      float zp = (C1[t][i] + ui)*s5v[i] + t5v[i];
      zp = zp >= 0.f ? zp : 0.2f*zp;
      atomicAdd(&accf[(w*16 + quad*4 + i)*8 + p], zp);
    }
  }
  __syncthreads();

  {
    const int o = tid & 63;
    #pragma unroll
    for (int g=0; g<2; ++g){
      const int p = (tid>>6) + g*4;
      xout[(p0+p)*64 + o] = accf[o*8+p] / 10.f;
    }
  }
}

// ---------------- G1: h6 = lrelu(W6@z), accumulate sum over N ----------------
__global__ __launch_bounds__(256) void g1_k(const float* __restrict__ W6,
   const float* __restrict__ x1t, const float* __restrict__ x2t, const float* __restrict__ x3t,
   const float* __restrict__ s6, const float* __restrict__ t6, float* __restrict__ gsum)
{
  __shared__ float Wl[16*132];
  __shared__ float Zl[16*260];
  const int tid = threadIdx.x;
  const int rb = blockIdx.x & 1;
  const int nt = (blockIdx.x >> 1) & 15;
  const int b  = blockIdx.x >> 5;
  const int r0 = rb*128;
  const int n0 = nt*256;
  const int ty = tid >> 4, tx = tid & 15;
  float acc[8][16];
  #pragma unroll
  for (int i=0;i<8;i++){
    #pragma unroll
    for (int j=0;j<16;j++) acc[i][j] = 0.f;
  }
  for (int kc=0; kc<12; kc++){
    __syncthreads();
    {
      const int r = tid >> 1, h = tid & 1;
      const float4* wp = (const float4*)(W6 + (size_t)(r0 + r)*192 + kc*16 + h*8);
      float tmp[8];
      *(float4*)&tmp[0] = wp[0];
      *(float4*)&tmp[4] = wp[1];
      #pragma unroll
      for (int u=0;u<8;u++) Wl[(h*8+u)*132 + r] = tmp[u];
    }
    {
      const float* arr = (kc < 4) ? x1t : (kc < 8) ? x2t : x3t;
      const int chofs = (kc & 3)*16;
      const float4* zp = (const float4*)(arr + ((size_t)(b*NN) + n0 + tid)*64 + chofs);
      float tmp[16];
      *(float4*)&tmp[0]  = zp[0];
      *(float4*)&tmp[4]  = zp[1];
      *(float4*)&tmp[8]  = zp[2];
      *(float4*)&tmp[12] = zp[3];
      #pragma unroll
      for (int u=0;u<16;u++) Zl[u*260 + tid] = tmp[u];
    }
    __syncthreads();
    #pragma unroll 4
    for (int k=0;k<16;k++){
      float wv[8], zv[16];
      *(float4*)&wv[0] = *(const float4*)(&Wl[k*132 + ty*8]);
      *(float4*)&wv[4] = *(const float4*)(&Wl[k*132 + ty*8 + 4]);
      #pragma unroll
      for (int jg=0;jg<4;jg++)
        *(float4*)&zv[jg*4] = *(const float4*)(&Zl[k*260 + jg*64 + tx*4]);
      #pragma unroll
      for (int i=0;i<8;i++){
        #pragma unroll
        for (int j=0;j<16;j++) acc[i][j] += wv[i]*zv[j];
      }
    }
  }
  #pragma unroll
  for (int i=0;i<8;i++){
    const int row = r0 + ty*8 + i;
    const float sv = s6[row], tv = t6[row];
    float sum = 0.f;
    #pragma unroll
    for (int j=0;j<16;j++) sum += lrelu(acc[i][j]*sv + tv);
    #pragma unroll
    for (int d=1; d<16; d<<=1) sum += __shfl_xor(sum, d, 64);
    if ((tid & 15) == 0) atomicAdd(&gsum[b*256 + row], sum);
  }
}

// ---------------- G2: c7 = W7[:, :256] @ (gsum/4096) ----------------
__global__ __launch_bounds__(256) void g2_k(const float* __restrict__ W7,
   const float* __restrict__ gsum, float* __restrict__ c7)
{
  const int b = blockIdx.x >> 1;
  const int o = (blockIdx.x & 1)*256 + threadIdx.x;
  const float* wr = W7 + (size_t)o*448;
  const float* gb = gsum + b*256;
  float a0=0.f,a1=0.f,a2=0.f,a3=0.f;
  #pragma unroll 4
  for (int c=0;c<256;c+=4){
    a0 += wr[c+0]*gb[c+0]; a1 += wr[c+1]*gb[c+1];
    a2 += wr[c+2]*gb[c+2]; a3 += wr[c+3]*gb[c+3];
  }
  c7[b*512+o] = ((a0+a1)+(a2+a3)) * (1.f/4096.f);
}

// ---------------- G3: h7 = lrelu((W7[:,256:]@z + c7)) -> max/sum over N ----------------
__global__ __launch_bounds__(256) void g3_k(const float* __restrict__ W7,
   const float* __restrict__ x1t, const float* __restrict__ x2t, const float* __restrict__ x3t,
   const float* __restrict__ c7, const float* __restrict__ s7, const float* __restrict__ t7,
   unsigned* __restrict__ x4e, float* __restrict__ x5s)
{
  __shared__ float Wl[16*132];
  __shared__ float Zl[16*260];
  const int tid = threadIdx.x;
  const int rb = blockIdx.x & 3;
  const int nt = (blockIdx.x >> 2) & 15;
  const int b  = blockIdx.x >> 6;
  const int r0 = rb*128;
  const int n0 = nt*256;
  const int ty = tid >> 4, tx = tid & 15;
  float acc[8][16];
  #pragma unroll
  for (int i=0;i<8;i++){
    #pragma unroll
    for (int j=0;j<16;j++) acc[i][j] = 0.f;
  }
  for (int kc=0; kc<12; kc++){
    __syncthreads();
    {
      const int r = tid >> 1, h = tid & 1;
      const float4* wp = (const float4*)(W7 + (size_t)(r0 + r)*448 + 256 + kc*16 + h*8);
      float tmp[8];
      *(float4*)&tmp[0] = wp[0];
      *(float4*)&tmp[4] = wp[1];
      #pragma unroll
      for (int u=0;u<8;u++) Wl[(h*8+u)*132 + r] = tmp[u];
    }
    {
      const float* arr = (kc < 4) ? x1t : (kc < 8) ? x2t : x3t;
      const int chofs = (kc & 3)*16;
      const float4* zp = (const float4*)(arr + ((size_t)(b*NN) + n0 + tid)*64 + chofs);
      float tmp[16];
      *(float4*)&tmp[0]  = zp[0];
      *(float4*)&tmp[4]  = zp[1];
      *(float4*)&tmp[8]  = zp[2];
      *(float4*)&tmp[12] = zp[3];
      #pragma unroll
      for (int u=0;u<16;u++) Zl[u*260 + tid] = tmp[u];
    }
    __syncthreads();
    #pragma unroll 4
    for (int k=0;k<16;k++){
      float wv[8], zv[16];
      *(float4*)&wv[0] = *(const float4*)(&Wl[k*132 + ty*8]);
      *(float4*)&wv[4] = *(const float4*)(&Wl[k*132 + ty*8 + 4]);
      #pragma unroll
      for (int jg=0;jg<4;jg++)
        *(float4*)&zv[jg*4] = *(const float4*)(&Zl[k*260 + jg*64 + tx*4]);
      #pragma unroll
      for (int i=0;i<8;i++){
        #pragma unroll
        for (int j=0;j<16;j++) acc[i][j] += wv[i]*zv[j];
      }
    }
  }
  #pragma unroll
  for (int i=0;i<8;i++){
    const int row = r0 + ty*8 + i;
    const float c7v = c7[b*512 + row];
    const float sv = s7[row], tv = t7[row];
    float mx = -__builtin_inff(), sum = 0.f;
    #pragma unroll
    for (int j=0;j<16;j++){
      float h = lrelu((acc[i][j] + c7v)*sv + tv);
      mx = fmaxf(mx, h); sum += h;
    }
    #pragma unroll
    for (int d=1; d<16; d<<=1){
      sum += __shfl_xor(sum, d, 64);
      mx = fmaxf(mx, __shfl_xor(mx, d, 64));
    }
    if ((tid & 15) == 0){
      atomicAdd(&x5s[b*512 + row], sum);
      atomicMax(&x4e[b*512 + row], fenc(mx));
    }
  }
}

// ---------------- G4: final linear ----------------
__global__ __launch_bounds__(128) void g4_k(const float* __restrict__ W8T,
  const unsigned* __restrict__ x4e, const float* __restrict__ x5s,
  const float* __restrict__ s8, const float* __restrict__ t8, float* __restrict__ out)
{
  const int b = blockIdx.x, j = threadIdx.x;
  float a0 = 0.f, a1 = 0.f;
  for (int o=0;o<512;o++){
    a0 += W8T[o*128 + j] * fdec(x4e[b*512 + o]);
    a1 += W8T[(512+o)*128 + j] * (x5s[b*512 + o] * (1.f/4096.f));
  }
  const float y = a0 + a1;
  out[b*128 + j] = lrelu(y*s8[j] + t8[j]);
}

extern "C" void kernel_launch(void* const* d_in, const int* in_sizes, int n_in,
                              void* d_out, int out_size, void* d_ws, size_t ws_size,
                              hipStream_t stream) {
  (void)in_sizes; (void)n_in; (void)out_size; (void)ws_size;
  const float* x  = (const float*)d_in[0];
  const float* W1 = (const float*)d_in[1];
  const float* W2 = (const float*)d_in[2];
  const float* W3 = (const float*)d_in[3];
  const float* W4 = (const float*)d_in[4];
  const float* W5 = (const float*)d_in[5];
  const float* W6 = (const float*)d_in[6];
  const float* W7 = (const float*)d_in[7];
  const float* W8 = (const float*)d_in[8];
  const float* s1 = (const float*)d_in[9];   const float* t1 = (const float*)d_in[10];
  const float* s2 = (const float*)d_in[11];  const float* t2 = (const float*)d_in[12];
  const float* s3 = (const float*)d_in[13];  const float* t3 = (const float*)d_in[14];
  const float* s4 = (const float*)d_in[15];  const float* t4 = (const float*)d_in[16];
  const float* s5 = (const float*)d_in[17];  const float* t5 = (const float*)d_in[18];
  const float* s6 = (const float*)d_in[19];  const float* t6 = (const float*)d_in[20];
  const float* s7 = (const float*)d_in[21];  const float* t7 = (const float*)d_in[22];
  const float* s8 = (const float*)d_in[23];  const float* t8 = (const float*)d_in[24];

  char* wsb = (char*)d_ws;
  size_t off = 0;
  auto alloc = [&](size_t bytes)->char* {
    char* p = wsb + off;
    off += (bytes + 255) & ~(size_t)255;
    return p;
  };
  int*      idx1 = (int*)alloc((size_t)BB*NN*KK*4);
  int*      idx2 = (int*)alloc((size_t)BB*NN*KK*4);
  int*      idx3 = (int*)alloc((size_t)BB*NN*KK*4);
  u64*      pkeys= (u64*)alloc((size_t)BB*NN*4*KK*8);
  float*    x1t  = (float*)alloc((size_t)BB*NN*64*4);
  float*    x2t  = (float*)alloc((size_t)BB*NN*64*4);
  float*    x3t  = (float*)alloc((size_t)BB*NN*64*4);
  unsigned short* Xh = (unsigned short*)alloc((size_t)BB*NN*64*2);
  unsigned short* Xl = (unsigned short*)alloc((size_t)BB*NN*64*2);
  float*    xxb  = (float*)alloc((size_t)BB*NN*4);
  float*    gsum = (float*)alloc((size_t)BB*256*4);
  unsigned* x4e  = (unsigned*)alloc((size_t)BB*512*4);
  float*    x5s  = (float*)alloc((size_t)BB*512*4);
  float*    c7   = (float*)alloc((size_t)BB*512*4);
  float*    W8T  = (float*)alloc(1024*128*4);
  unsigned short* W1h  = (unsigned short*)alloc(64*32*2);
  unsigned short* W1l  = (unsigned short*)alloc(64*32*2);
  unsigned short* W2h  = (unsigned short*)alloc(64*64*2);
  unsigned short* W2l  = (unsigned short*)alloc(64*64*2);
  unsigned short* W3dh = (unsigned short*)alloc(64*64*2);
  unsigned short* W3dl = (unsigned short*)alloc(64*64*2);
  unsigned short* W3qh = (unsigned short*)alloc(64*64*2);
  unsigned short* W3ql = (unsigned short*)alloc(64*64*2);
  unsigned short* W4h  = (unsigned short*)alloc(64*64*2);
  unsigned short* W4l  = (unsigned short*)alloc(64*64*2);
  unsigned short* W5dh = (unsigned short*)alloc(64*64*2);
  unsigned short* W5dl = (unsigned short*)alloc(64*64*2);
  unsigned short* W5qh = (unsigned short*)alloc(64*64*2);
  unsigned short* W5ql = (unsigned short*)alloc(64*64*2);

  prep_k<<<64,256,0,stream>>>(W1,W2,W3,W4,W5,W8, W8T,
                              W1h,W1l,W2h,W2l,
                              W3dh,W3dl,W3qh,W3ql,W4h,W4l, W5dh,W5dl,W5qh,W5ql);
  knn2d_k<<<BB*64*4,256,0,stream>>>(x, pkeys);
  kmerge_k<<<BB*NN/256,256,0,stream>>>(pkeys, idx1);
  edge1_k<<<BB*NN/8,256,0,stream>>>(x, idx1, W1h,W1l,W2h,W2l, s1,t1,s2,t2, x1t);
  cvt_k<<<BB*NN*8/256,256,0,stream>>>(x1t, Xh, Xl, xxb);
  knn64_k<<<BB*64*4,256,0,stream>>>(Xh, Xl, xxb, pkeys);
  kmerge_k<<<BB*NN/256,256,0,stream>>>(pkeys, idx2);
  edge2_k<<<BB*NN/8,256,0,stream>>>(x1t, idx2, W3dh,W3dl,W3qh,W3ql,W4h,W4l, s3,t3,s4,t4, x2t);
  cvt_k<<<BB*NN*8/256,256,0,stream>>>(x2t, Xh, Xl, xxb);
  knn64_k<<<BB*64*4,256,0,stream>>>(Xh, Xl, xxb, pkeys);
  kmerge_k<<<BB*NN/256,256,0,stream>>>(pkeys, idx3);
  edge3_k<<<BB*NN/8,256,0,stream>>>(x2t, idx3, W5dh,W5dl,W5qh,W5ql, s5,t5, x3t);
  hipMemsetAsync(gsum, 0, (size_t)BB*256*4 + (size_t)BB*512*4*2, stream);
  g1_k<<<256,256,0,stream>>>(W6, x1t,x2t,x3t, s6,t6, gsum);
  g2_k<<<16,256,0,stream>>>(W7, gsum, c7);
  g3_k<<<512,256,0,stream>>>(W7, x1t,x2t,x3t, c7, s7,t7, x4e, x5s);
  g4_k<<<BB,128,0,stream>>>(W8T, x4e, x5s, s8,t8, (float*)d_out);
}

// Round 14
// 1056.588 us; speedup vs baseline: 1.1303x; 1.1303x over previous
//
#include <hip/hip_runtime.h>

#define BB 8
#define NN 4096
#define KK 10
#define CAP 24
#define TT 4
typedef unsigned long long u64;
typedef __attribute__((ext_vector_type(8))) short bf16x8;
typedef __attribute__((ext_vector_type(4))) float f32x4;

__device__ __forceinline__ float lrelu(float v){ return v >= 0.f ? v : 0.2f*v; }
__device__ __forceinline__ float bc(float v, int l){
  return __int_as_float(__builtin_amdgcn_readlane(__float_as_int(v), l));
}
__device__ __forceinline__ unsigned fenc(float f){
  unsigned u = __float_as_uint(f);
  return u ^ (((unsigned)((int)u >> 31)) | 0x80000000u);
}
__device__ __forceinline__ float fdec(unsigned e){
  return (e & 0x80000000u) ? __uint_as_float(e & 0x7fffffffu) : __uint_as_float(~e);
}

// ---------------- weight prep: transposes + split-bf16 conversions ----------------
__global__ __launch_bounds__(256) void prep_k(
    const float* __restrict__ W1, const float* __restrict__ W2, const float* __restrict__ W3,
    const float* __restrict__ W4, const float* __restrict__ W5, const float* __restrict__ W8,
    float* __restrict__ W1T, float* __restrict__ W2T, float* __restrict__ W5T, float* __restrict__ W8T,
    unsigned short* __restrict__ W3dh, unsigned short* __restrict__ W3dl,
    unsigned short* __restrict__ W3qh, unsigned short* __restrict__ W3ql,
    unsigned short* __restrict__ W4h,  unsigned short* __restrict__ W4l)
{
  const int t = blockIdx.x*256 + threadIdx.x;
  const int stride = gridDim.x*256;
  for (int i=t; i<64*14; i+=stride){ int o=i/14, c=i%14; W1T[c*64+o]=W1[i]; }
  for (int i=t; i<64*64; i+=stride){ int o=i>>6, c=i&63; W2T[c*64+o]=W2[i]; }
  for (int i=t; i<64*128; i+=stride){ int o=i>>7, c=i&127; W5T[c*64+o]=W5[i]; }
  for (int i=t; i<128*1024; i+=stride){ int o=i>>10, c=i&1023; W8T[c*128+o]=W8[i]; }
  // split-bf16 conversions, row-major [o][k]
  for (int i=t; i<64*64; i+=stride){
    int o=i>>6, c=i&63;
    float f = W3[o*128 + c];
    unsigned u = __float_as_uint(f);
    W3dh[i] = (unsigned short)(u >> 16);
    float lo = f - __uint_as_float(u & 0xffff0000u);
    W3dl[i] = (unsigned short)(__float_as_uint(lo) >> 16);
  }
  for (int i=t; i<64*64; i+=stride){
    int o=i>>6, c=i&63;
    float f = W3[o*128 + 64 + c];
    unsigned u = __float_as_uint(f);
    W3qh[i] = (unsigned short)(u >> 16);
    float lo = f - __uint_as_float(u & 0xffff0000u);
    W3ql[i] = (unsigned short)(__float_as_uint(lo) >> 16);
  }
  for (int i=t; i<64*64; i+=stride){
    float f = W4[i];
    unsigned u = __float_as_uint(f);
    W4h[i] = (unsigned short)(u >> 16);
    float lo = f - __uint_as_float(u & 0xffff0000u);
    W4l[i] = (unsigned short)(__float_as_uint(lo) >> 16);
  }
}

// ---------------- one-time fp32 -> split bf16 (hi/lo) + squared norms ----------------
__global__ __launch_bounds__(256) void cvt_k(const float* __restrict__ xin,
    unsigned short* __restrict__ Xh, unsigned short* __restrict__ Xl, float* __restrict__ xx)
{
  const int gid = blockIdx.x*256 + threadIdx.x;   // BB*NN*8 threads
  const int p = gid >> 3, c8 = (gid & 7) << 3;
  const float* src = xin + (size_t)p*64 + c8;
  float fv[8];
  *(float4*)&fv[0] = *(const float4*)(src);
  *(float4*)&fv[4] = *(const float4*)(src + 4);
  unsigned hp[4], lp[4];
  float ssq = 0.f;
  #pragma unroll
  for (int e=0; e<4; e++){
    float f0 = fv[2*e], f1 = fv[2*e+1];
    ssq += f0*f0 + f1*f1;
    unsigned u0 = __float_as_uint(f0), u1 = __float_as_uint(f1);
    hp[e] = (u0 >> 16) | (u1 & 0xffff0000u);
    float l0 = f0 - __uint_as_float(u0 & 0xffff0000u);
    float l1 = f1 - __uint_as_float(u1 & 0xffff0000u);
    lp[e] = (__float_as_uint(l0) >> 16) | (__float_as_uint(l1) & 0xffff0000u);
  }
  *(uint4*)(Xh + (size_t)p*64 + c8) = uint4{hp[0],hp[1],hp[2],hp[3]};
  *(uint4*)(Xl + (size_t)p*64 + c8) = uint4{lp[0],lp[1],lp[2],lp[3]};
  ssq += __shfl_xor(ssq, 1, 64);
  ssq += __shfl_xor(ssq, 2, 64);
  ssq += __shfl_xor(ssq, 4, 64);
  if ((gid & 7) == 0) xx[p] = ssq;
}

// ---------------- knn over first 2 channels: two-phase selection ----------------
__global__ __launch_bounds__(256) void knn2d_k(const float* __restrict__ x, u64* __restrict__ pk)
{
  __shared__ float px[1024], py[1024], pxx[1024];
  __shared__ unsigned cnt[64];
  __shared__ u64 lst[CAP][64];
  const int tid = threadIdx.x;
  const int b  = blockIdx.x >> 8;
  const int qt = (blockIdx.x >> 2) & 63;
  const int h  = blockIdx.x & 3;
  const int q0 = qt*64;
  const int m0g = h*1024;
  const float* xb = x + (size_t)b*7*NN;
  for (int m = tid; m < 1024; m += 256){
    float a = xb[m0g + m], c = xb[NN + m0g + m];
    px[m] = a; py[m] = c; pxx[m] = a*a + c*c;
  }
  if (tid < 64) cnt[tid] = 0;
  __syncthreads();

  const int ty = tid >> 4, tx = tid & 15;
  const int qr = ty*4;
  float qx4[4], qy4[4], q24[4];
  #pragma unroll
  for (int i=0;i<4;i++){
    float a = xb[q0+qr+i], c = xb[NN + q0+qr+i];
    qx4[i] = a; qy4[i] = c; q24[i] = a*a + c*c;
  }

  float bv[4][TT];
  #pragma unroll
  for (int i=0;i<4;i++){
    #pragma unroll
    for (int s=0;s<TT;s++) bv[i][s] = -__builtin_inff();
  }

  for (int ot=0; ot<8; ot++){
    #pragma unroll
    for (int j=0;j<8;j++){
      const int ml = ot*128 + j*16 + tx;
      const float cmx = px[ml], cmy = py[ml], cm2 = pxx[ml];
      #pragma unroll
      for (int i=0;i<4;i++){
        float dot = qx4[i]*cmx + qy4[i]*cmy;
        float v = (-q24[i]) - (-2.f*dot) - cm2;
        float c = v;
        #pragma unroll
        for (int s=0;s<TT;s++){
          float nb = fmaxf(bv[i][s], c);
          c = fminf(bv[i][s], c);
          bv[i][s] = nb;
        }
      }
    }
  }

  float thr[4];
  #pragma unroll
  for (int i=0;i<4;i++){
    float m = 0.f;
    #pragma unroll
    for (int k=0;k<10;k++){
      float hh = bv[i][0];
      m = hh;
      m = fmaxf(m, __shfl_xor(m, 1, 64));
      m = fmaxf(m, __shfl_xor(m, 2, 64));
      m = fmaxf(m, __shfl_xor(m, 4, 64));
      m = fmaxf(m, __shfl_xor(m, 8, 64));
      if (k < 9){
        if (hh == m){
          #pragma unroll
          for (int s=0;s<TT-1;s++) bv[i][s] = bv[i][s+1];
          bv[i][TT-1] = -__builtin_inff();
        }
      }
    }
    thr[i] = m;
  }

  for (int ot=0; ot<8; ot++){
    #pragma unroll
    for (int j=0;j<8;j++){
      const int ml = ot*128 + j*16 + tx;
      const float cmx = px[ml], cmy = py[ml], cm2 = pxx[ml];
      const unsigned mk = ~(unsigned)(m0g + ml);
      #pragma unroll
      for (int i=0;i<4;i++){
        float dot = qx4[i]*cmx + qy4[i]*cmy;
        float v = (-q24[i]) - (-2.f*dot) - cm2;
        if (v >= thr[i]){
          u64 key = ((u64)fenc(v) << 32) | mk;
          const int r = qr + i;
          unsigned slot = atomicAdd(&cnt[r], 1u);
          if (slot < CAP) lst[slot][r] = key;
        }
      }
    }
  }
  __syncthreads();

  if (tid < 64){
    int n = (int)cnt[tid]; if (n > CAP) n = CAP;
    u64* op = pk + (((size_t)b*NN + q0 + tid)*4 + h)*KK;
    for (int k=0;k<KK;k++){
      u64 best = 0ull; int bi = 0;
      for (int s=0;s<n;s++){
        u64 v2 = lst[s][tid];
        if (v2 > best){ best = v2; bi = s; }
      }
      if (best) lst[bi][tid] = 0ull;
      op[k] = best;
    }
  }
}

// ---------------- knn over 64 channels: two-phase selection (top-TT network) --------
__global__ __launch_bounds__(256) void knn64_k(const unsigned short* __restrict__ Xh,
    const unsigned short* __restrict__ Xl, const float* __restrict__ xx, u64* __restrict__ pk)
{
  __shared__ unsigned short Ch[64*72], Cl[64*72];
  __shared__ float cxx[64];
  __shared__ unsigned cnt[64];
  __shared__ u64 lst[CAP][64];
  const int tid = threadIdx.x;
  const int b  = blockIdx.x >> 8;
  const int qt = (blockIdx.x >> 2) & 63;
  const int h  = blockIdx.x & 3;
  const int q0 = qt*64;
  const int m0g = h*1024;
  const unsigned short* Xhb = Xh + (size_t)b*NN*64;
  const unsigned short* Xlb = Xl + (size_t)b*NN*64;
  const float* xxb = xx + (size_t)b*NN;

  const int sp = tid >> 2;
  const int sc = (tid & 3) << 4;

  const int lane = tid & 63;
  const int w    = tid >> 6;
  const int col  = lane & 15;
  const int quad = (tid >> 4) & 3;
  const int qr   = (tid >> 4)*4;

  const size_t abase = (size_t)(q0 + w*16 + col)*64 + quad*8;
  bf16x8 Ah0 = *(const bf16x8*)(Xhb + abase);
  bf16x8 Ah1 = *(const bf16x8*)(Xhb + abase + 32);
  bf16x8 Al0 = *(const bf16x8*)(Xlb + abase);
  bf16x8 Al1 = *(const bf16x8*)(Xlb + abase + 32);

  float qx4[4];
  #pragma unroll
  for (int i=0;i<4;i++) qx4[i] = xxb[q0 + qr + i];

  if (tid < 64) cnt[tid] = 0;

  float bv[4][TT];
  #pragma unroll
  for (int i=0;i<4;i++){
    #pragma unroll
    for (int s=0;s<TT;s++) bv[i][s] = -__builtin_inff();
  }

  for (int ct=0; ct<16; ct++){
    const int m0 = m0g + ct*64;
    __syncthreads();
    {
      const uint4* sh = (const uint4*)(Xhb + (size_t)(m0+sp)*64 + sc);
      const uint4* sl = (const uint4*)(Xlb + (size_t)(m0+sp)*64 + sc);
      uint4 h0 = sh[0], h1 = sh[1], l0 = sl[0], l1 = sl[1];
      *(uint4*)(&Ch[sp*72 + sc])     = h0;
      *(uint4*)(&Ch[sp*72 + sc + 8]) = h1;
      *(uint4*)(&Cl[sp*72 + sc])     = l0;
      *(uint4*)(&Cl[sp*72 + sc + 8]) = l1;
      if (tid < 64) cxx[tid] = xxb[m0 + tid];
    }
    __syncthreads();

    #pragma unroll
    for (int j=0;j<4;j++){
      const int boff = (j*16 + col)*72 + quad*8;
      bf16x8 Bh0 = *(const bf16x8*)(&Ch[boff]);
      bf16x8 Bh1 = *(const bf16x8*)(&Ch[boff+32]);
      bf16x8 Bl0 = *(const bf16x8*)(&Cl[boff]);
      bf16x8 Bl1 = *(const bf16x8*)(&Cl[boff+32]);
      f32x4 d = {0.f,0.f,0.f,0.f};
      d = __builtin_amdgcn_mfma_f32_16x16x32_bf16(Al0, Bh0, d, 0,0,0);
      d = __builtin_amdgcn_mfma_f32_16x16x32_bf16(Ah0, Bl0, d, 0,0,0);
      d = __builtin_amdgcn_mfma_f32_16x16x32_bf16(Ah0, Bh0, d, 0,0,0);
      d = __builtin_amdgcn_mfma_f32_16x16x32_bf16(Al1, Bh1, d, 0,0,0);
      d = __builtin_amdgcn_mfma_f32_16x16x32_bf16(Ah1, Bl1, d, 0,0,0);
      d = __builtin_amdgcn_mfma_f32_16x16x32_bf16(Ah1, Bh1, d, 0,0,0);

      const float cx = cxx[j*16 + col];
      #pragma unroll
      for (int i=0;i<4;i++){
        float v = (-qx4[i]) - (-2.f*d[i]) - cx;
        float c = v;
        #pragma unroll
        for (int s=0;s<TT;s++){
          float nb = fmaxf(bv[i][s], c);
          c = fminf(bv[i][s], c);
          bv[i][s] = nb;
        }
      }
    }
  }

  float thr[4];
  #pragma unroll
  for (int i=0;i<4;i++){
    float m = 0.f;
    #pragma unroll
    for (int k=0;k<10;k++){
      float hh = bv[i][0];
      m = hh;
      m = fmaxf(m, __shfl_xor(m, 1, 64));
      m = fmaxf(m, __shfl_xor(m, 2, 64));
      m = fmaxf(m, __shfl_xor(m, 4, 64));
      m = fmaxf(m, __shfl_xor(m, 8, 64));
      if (k < 9){
        if (hh == m){
          #pragma unroll
          for (int s=0;s<TT-1;s++) bv[i][s] = bv[i][s+1];
          bv[i][TT-1] = -__builtin_inff();
        }
      }
    }
    thr[i] = m;
  }

  for (int ct=0; ct<16; ct++){
    const int m0 = m0g + ct*64;
    __syncthreads();
    {
      const uint4* sh = (const uint4*)(Xhb + (size_t)(m0+sp)*64 + sc);
      const uint4* sl = (const uint4*)(Xlb + (size_t)(m0+sp)*64 + sc);
      uint4 h0 = sh[0], h1 = sh[1], l0 = sl[0], l1 = sl[1];
      *(uint4*)(&Ch[sp*72 + sc])     = h0;
      *(uint4*)(&Ch[sp*72 + sc + 8]) = h1;
      *(uint4*)(&Cl[sp*72 + sc])     = l0;
      *(uint4*)(&Cl[sp*72 + sc + 8]) = l1;
      if (tid < 64) cxx[tid] = xxb[m0 + tid];
    }
    __syncthreads();

    #pragma unroll
    for (int j=0;j<4;j++){
      const int boff = (j*16 + col)*72 + quad*8;
      bf16x8 Bh0 = *(const bf16x8*)(&Ch[boff]);
      bf16x8 Bh1 = *(const bf16x8*)(&Ch[boff+32]);
      bf16x8 Bl0 = *(const bf16x8*)(&Cl[boff]);
      bf16x8 Bl1 = *(const bf16x8*)(&Cl[boff+32]);
      f32x4 d = {0.f,0.f,0.f,0.f};
      d = __builtin_amdgcn_mfma_f32_16x16x32_bf16(Al0, Bh0, d, 0,0,0);
      d = __builtin_amdgcn_mfma_f32_16x16x32_bf16(Ah0, Bl0, d, 0,0,0);
      d = __builtin_amdgcn_mfma_f32_16x16x32_bf16(Ah0, Bh0, d, 0,0,0);
      d = __builtin_amdgcn_mfma_f32_16x16x32_bf16(Al1, Bh1, d, 0,0,0);
      d = __builtin_amdgcn_mfma_f32_16x16x32_bf16(Ah1, Bl1, d, 0,0,0);
      d = __builtin_amdgcn_mfma_f32_16x16x32_bf16(Ah1, Bh1, d, 0,0,0);

      const int m = m0 + j*16 + col;
      const float cx = cxx[j*16 + col];
      const unsigned mk = ~(unsigned)m;
      #pragma unroll
      for (int i=0;i<4;i++){
        float v = (-qx4[i]) - (-2.f*d[i]) - cx;
        if (v >= thr[i]){
          u64 key = ((u64)fenc(v) << 32) | mk;
          const int r = qr + i;
          unsigned slot = atomicAdd(&cnt[r], 1u);
          if (slot < CAP) lst[slot][r] = key;
        }
      }
    }
  }
  __syncthreads();

  if (tid < 64){
    int n = (int)cnt[tid]; if (n > CAP) n = CAP;
    u64* op = pk + (((size_t)b*NN + q0 + tid)*4 + h)*KK;
    for (int k=0;k<KK;k++){
      u64 best = 0ull; int bi = 0;
      for (int s=0;s<n;s++){
        u64 v2 = lst[s][tid];
        if (v2 > best){ best = v2; bi = s; }
      }
      if (best) lst[bi][tid] = 0ull;
      op[k] = best;
    }
  }
}

// ---------------- merge four sorted-desc 10-key quarters -> final idx ----------------
__global__ __launch_bounds__(256) void kmerge_k(const u64* __restrict__ pk, int* __restrict__ idxo)
{
  const int q = blockIdx.x*256 + threadIdx.x;   // q < BB*NN
  const u64* A = pk + (size_t)q*(4*KK);
  int* op = idxo + (size_t)q*KK;
  int ia = 0, ib = 0, ic = 0, id = 0;
  #pragma unroll
  for (int k=0;k<KK;k++){
    u64 a  = (ia < KK) ? A[ia]        : 0ull;
    u64 b2 = (ib < KK) ? A[KK + ib]   : 0ull;
    u64 c2 = (ic < KK) ? A[2*KK + ic] : 0ull;
    u64 d2 = (id < KK) ? A[3*KK + id] : 0ull;
    u64 m1 = a >= b2 ? a : b2;  int s1 = a >= b2 ? 0 : 1;
    u64 m2 = c2 >= d2 ? c2 : d2; int s2 = c2 >= d2 ? 2 : 3;
    u64 mm = m1 >= m2 ? m1 : m2; int ss = m1 >= m2 ? s1 : s2;
    op[k] = (int)(~(unsigned)mm);
    if (ss == 0) ia++; else if (ss == 1) ib++; else if (ss == 2) ic++; else id++;
  }
}

// ---------------- edge conv 1: graph_feature1 + W1 + W2 + mean (scalar, measured) ----
__global__ __launch_bounds__(256) void edge1_k(const float* __restrict__ x, const int* __restrict__ idx,
    const float* __restrict__ W1T, const float* __restrict__ W2T,
    const float* __restrict__ s1, const float* __restrict__ t1,
    const float* __restrict__ s2, const float* __restrict__ t2,
    float* __restrict__ x1t)
{
  const int lane = threadIdx.x & 63;
  const int pt = (blockIdx.x << 2) + (threadIdx.x >> 6);
  const int b = pt >> 12, n = pt & 4095;
  const float* xb = x + (size_t)b*7*NN;
  float w1r[14], w2r[64];
  #pragma unroll
  for (int c=0;c<14;c++) w1r[c] = W1T[c*64 + lane];
  #pragma unroll
  for (int c=0;c<64;c++) w2r[c] = W2T[c*64 + lane];
  const float s1o=s1[lane], t1o=t1[lane], s2o=s2[lane], t2o=t2[lane];
  const float xq = (lane < 7) ? xb[lane*NN + n] : 0.f;
  const float xq0 = bc(xq,0), xq1 = bc(xq,1);
  float qy1 = 0.f;
  #pragma unroll
  for (int c=0;c<7;c++) qy1 += w1r[7+c]*bc(xq,c);
  const int* ip = idx + (size_t)pt*KK;
  float acc = 0.f;
  for (int j=0;j<KK;j++){
    const int ij = ip[j];
    const float xg = (lane < 7) ? xb[lane*NN + ij] : 0.f;
    float y1 = qy1;
    y1 += w1r[0]*(bc(xg,0) - xq0);
    y1 += w1r[1]*(bc(xg,1) - xq1);
    #pragma unroll
    for (int c=2;c<7;c++) y1 += w1r[c]*bc(xg,c);
    const float z1 = lrelu(y1*s1o + t1o);
    float p0=0.f,p1=0.f,p2=0.f,p3=0.f;
    #pragma unroll
    for (int c=0;c<64;c+=4){
      p0 += w2r[c+0]*bc(z1,c+0);
      p1 += w2r[c+1]*bc(z1,c+1);
      p2 += w2r[c+2]*bc(z1,c+2);
      p3 += w2r[c+3]*bc(z1,c+3);
    }
    acc += lrelu(((p0+p1)+(p2+p3))*s2o + t2o);
  }
  x1t[(size_t)pt*64 + lane] = acc / 10.f;
}

// ---------------- edge conv 2: MFMA split-bf16 (GEMM1: W3d@d + W3q@xq, GEMM2: W4@z3) --
__global__ __launch_bounds__(256) void edge2_k(const float* __restrict__ x1t, const int* __restrict__ idx,
    const unsigned short* __restrict__ W3dh, const unsigned short* __restrict__ W3dl,
    const unsigned short* __restrict__ W3qh, const unsigned short* __restrict__ W3ql,
    const unsigned short* __restrict__ W4h,  const unsigned short* __restrict__ W4l,
    const float* __restrict__ s3, const float* __restrict__ t3,
    const float* __restrict__ s4, const float* __restrict__ t4,
    float* __restrict__ xout)
{
  __shared__ unsigned short Zh[80*72], Zl[80*72];   // D staging -> z3 overlay
  __shared__ unsigned short Qh[16*72], Ql[16*72];
  __shared__ float accf[64*8];
  const int tid = threadIdx.x;
  const size_t p0 = (size_t)blockIdx.x * 8;

  ((float2*)accf)[tid] = float2{0.f, 0.f};

  #pragma unroll
  for (int pass=0; pass<2; ++pass){
    const int col = pass*64 + (tid>>2);
    const int sc16 = (tid&3)*16;
    if (col < 88){
      float dv[16];
      if (col < 80){
        const int p = col/10, j = col - p*10;
        const size_t pt = p0 + p;
        const int bb = (int)(pt >> 12);
        const int ij = idx[pt*KK + j];
        const float* gs = x1t + ((size_t)bb*NN + ij)*64 + sc16;
        const float* qs = x1t + pt*64 + sc16;
        #pragma unroll
        for (int e=0;e<4;e++){
          float4 g4 = *(const float4*)(gs + e*4);
          float4 q4 = *(const float4*)(qs + e*4);
          dv[e*4+0]=g4.x-q4.x; dv[e*4+1]=g4.y-q4.y; dv[e*4+2]=g4.z-q4.z; dv[e*4+3]=g4.w-q4.w;
        }
      } else {
        const int cl = col - 80;
        const float* qs = x1t + (size_t)(p0+cl)*64 + sc16;
        #pragma unroll
        for (int e=0;e<4;e++){
          float4 q4 = *(const float4*)(qs + e*4);
          dv[e*4+0]=q4.x; dv[e*4+1]=q4.y; dv[e*4+2]=q4.z; dv[e*4+3]=q4.w;
        }
      }
      unsigned hp[8], lp[8];
      #pragma unroll
      for (int e=0;e<8;e++){
        float f0 = dv[2*e], f1 = dv[2*e+1];
        unsigned u0 = __float_as_uint(f0), u1 = __float_as_uint(f1);
        hp[e] = (u0 >> 16) | (u1 & 0xffff0000u);
        float l0 = f0 - __uint_as_float(u0 & 0xffff0000u);
        float l1 = f1 - __uint_as_float(u1 & 0xffff0000u);
        lp[e] = (__float_as_uint(l0) >> 16) | (__float_as_uint(l1) & 0xffff0000u);
      }
      if (col < 80){
        *(uint4*)(&Zh[col*72 + sc16])     = uint4{hp[0],hp[1],hp[2],hp[3]};
        *(uint4*)(&Zh[col*72 + sc16 + 8]) = uint4{hp[4],hp[5],hp[6],hp[7]};
        *(uint4*)(&Zl[col*72 + sc16])     = uint4{lp[0],lp[1],lp[2],lp[3]};
        *(uint4*)(&Zl[col*72 + sc16 + 8]) = uint4{lp[4],lp[5],lp[6],lp[7]};
      } else {
        const int cl = col - 80;
        *(uint4*)(&Qh[cl*72 + sc16])     = uint4{hp[0],hp[1],hp[2],hp[3]};
        *(uint4*)(&Qh[cl*72 + sc16 + 8]) = uint4{hp[4],hp[5],hp[6],hp[7]};
        *(uint4*)(&Ql[cl*72 + sc16])     = uint4{lp[0],lp[1],lp[2],lp[3]};
        *(uint4*)(&Ql[cl*72 + sc16 + 8]) = uint4{lp[4],lp[5],lp[6],lp[7]};
      }
    } else if (col < 96){
      const int cl = col - 80;
      const uint4 z{0u,0u,0u,0u};
      *(uint4*)(&Qh[cl*72 + sc16])     = z;
      *(uint4*)(&Qh[cl*72 + sc16 + 8]) = z;
      *(uint4*)(&Ql[cl*72 + sc16])     = z;
      *(uint4*)(&Ql[cl*72 + sc16 + 8]) = z;
    }
  }
  __syncthreads();

  const int lane = tid & 63;
  const int w    = tid >> 6;
  const int colL = lane & 15;
  const int quad = lane >> 4;
  const int arow = (w*16 + colL)*64 + quad*8;

  bf16x8 Adh0 = *(const bf16x8*)(W3dh + arow);
  bf16x8 Adh1 = *(const bf16x8*)(W3dh + arow + 32);
  bf16x8 Adl0 = *(const bf16x8*)(W3dl + arow);
  bf16x8 Adl1 = *(const bf16x8*)(W3dl + arow + 32);

  f32x4 C1[5];
  #pragma unroll
  for (int t=0;t<5;t++){
    const int boff = (t*16 + colL)*72 + quad*8;
    bf16x8 Bh0 = *(const bf16x8*)(&Zh[boff]);
    bf16x8 Bh1 = *(const bf16x8*)(&Zh[boff+32]);
    bf16x8 Bl0 = *(const bf16x8*)(&Zl[boff]);
    bf16x8 Bl1 = *(const bf16x8*)(&Zl[boff+32]);
    f32x4 d = {0.f,0.f,0.f,0.f};
    d = __builtin_amdgcn_mfma_f32_16x16x32_bf16(Adl0, Bh0, d, 0,0,0);
    d = __builtin_amdgcn_mfma_f32_16x16x32_bf16(Adh0, Bl0, d, 0,0,0);
    d = __builtin_amdgcn_mfma_f32_16x16x32_bf16(Adh0, Bh0, d, 0,0,0);
    d = __builtin_amdgcn_mfma_f32_16x16x32_bf16(Adl1, Bh1, d, 0,0,0);
    d = __builtin_amdgcn_mfma_f32_16x16x32_bf16(Adh1, Bl1, d, 0,0,0);
    d = __builtin_amdgcn_mfma_f32_16x16x32_bf16(Adh1, Bh1, d, 0,0,0);
    C1[t] = d;
  }
  f32x4 Cu;
  {
    bf16x8 Aqh0 = *(const bf16x8*)(W3qh + arow);
    bf16x8 Aqh1 = *(const bf16x8*)(W3qh + arow + 32);
    bf16x8 Aql0 = *(const bf16x8*)(W3ql + arow);
    bf16x8 Aql1 = *(const bf16x8*)(W3ql + arow + 32);
    const int boff = colL*72 + quad*8;
    bf16x8 Bh0 = *(const bf16x8*)(&Qh[boff]);
    bf16x8 Bh1 = *(const bf16x8*)(&Qh[boff+32]);
    bf16x8 Bl0 = *(const bf16x8*)(&Ql[boff]);
    bf16x8 Bl1 = *(const bf16x8*)(&Ql[boff+32]);
    f32x4 d = {0.f,0.f,0.f,0.f};
    d = __builtin_amdgcn_mfma_f32_16x16x32_bf16(Aql0, Bh0, d, 0,0,0);
    d = __builtin_amdgcn_mfma_f32_16x16x32_bf16(Aqh0, Bl0, d, 0,0,0);
    d = __builtin_amdgcn_mfma_f32_16x16x32_bf16(Aqh0, Bh0, d, 0,0,0);
    d = __builtin_amdgcn_mfma_f32_16x16x32_bf16(Aql1, Bh1, d, 0,0,0);
    d = __builtin_amdgcn_mfma_f32_16x16x32_bf16(Aqh1, Bl1, d, 0,0,0);
    d = __builtin_amdgcn_mfma_f32_16x16x32_bf16(Aqh1, Bh1, d, 0,0,0);
    Cu = d;
  }

  float s3v[4], t3v[4], s4v[4], t4v[4];
  #pragma unroll
  for (int i=0;i<4;i++){
    const int o = w*16 + quad*4 + i;
    s3v[i]=s3[o]; t3v[i]=t3[o]; s4v[i]=s4[o]; t4v[i]=t4[o];
  }

  __syncthreads();

  #pragma unroll
  for (int t=0;t<5;t++){
    const int gc = t*16 + colL;
    const int p  = gc/10;
    const int srcb = (((lane & 48) | p) << 2);
    float z[4];
    #pragma unroll
    for (int i=0;i<4;i++){
      float ui = __int_as_float(__builtin_amdgcn_ds_bpermute(srcb, __float_as_int(Cu[i])));
      float zp = (C1[t][i] + ui)*s3v[i] + t3v[i];
      z[i] = zp >= 0.f ? zp : 0.2f*zp;
    }
    unsigned u0=__float_as_uint(z[0]), u1=__float_as_uint(z[1]);
    unsigned u2=__float_as_uint(z[2]), u3=__float_as_uint(z[3]);
    unsigned h01 = (u0>>16) | (u1 & 0xffff0000u);
    unsigned h23 = (u2>>16) | (u3 & 0xffff0000u);
    float l0 = z[0]-__uint_as_float(u0&0xffff0000u);
    float l1 = z[1]-__uint_as_float(u1&0xffff0000u);
    float l2 = z[2]-__uint_as_float(u2&0xffff0000u);
    float l3 = z[3]-__uint_as_float(u3&0xffff0000u);
    unsigned l01 = (__float_as_uint(l0)>>16) | (__float_as_uint(l1)&0xffff0000u);
    unsigned l23 = (__float_as_uint(l2)>>16) | (__float_as_uint(l3)&0xffff0000u);
    const int rb = w*16 + quad*4;
    *(uint2*)(&Zh[gc*72 + rb]) = uint2{h01,h23};
    *(uint2*)(&Zl[gc*72 + rb]) = uint2{l01,l23};
  }
  __syncthreads();

  bf16x8 A4h0 = *(const bf16x8*)(W4h + arow);
  bf16x8 A4h1 = *(const bf16x8*)(W4h + arow + 32);
  bf16x8 A4l0 = *(const bf16x8*)(W4l + arow);
  bf16x8 A4l1 = *(const bf16x8*)(W4l + arow + 32);
  #pragma unroll
  for (int t=0;t<5;t++){
    const int boff = (t*16 + colL)*72 + quad*8;
    bf16x8 Bh0 = *(const bf16x8*)(&Zh[boff]);
    bf16x8 Bh1 = *(const bf16x8*)(&Zh[boff+32]);
    bf16x8 Bl0 = *(const bf16x8*)(&Zl[boff]);
    bf16x8 Bl1 = *(const bf16x8*)(&Zl[boff+32]);
    f32x4 d = {0.f,0.f,0.f,0.f};
    d = __builtin_amdgcn_mfma_f32_16x16x32_bf16(A4l0, Bh0, d, 0,0,0);
    d = __builtin_amdgcn_mfma_f32_16x16x32_bf16(A4h0, Bl0, d, 0,0,0);
    d = __builtin_amdgcn_mfma_f32_16x16x32_bf16(A4h0, Bh0, d, 0,0,0);
    d = __builtin_amdgcn_mfma_f32_16x16x32_bf16(A4l1, Bh1, d, 0,0,0);
    d = __builtin_amdgcn_mfma_f32_16x16x32_bf16(A4h1, Bl1, d, 0,0,0);
    d = __builtin_amdgcn_mfma_f32_16x16x32_bf16(A4h1, Bh1, d, 0,0,0);
    const int gc = t*16 + colL;
    const int p  = gc/10;
    #pragma unroll
    for (int i=0;i<4;i++){
      float v = d[i]*s4v[i] + t4v[i];
      v = v >= 0.f ? v : 0.2f*v;
      atomicAdd(&accf[(w*16 + quad*4 + i)*8 + p], v);
    }
  }
  __syncthreads();

  {
    const int o = tid & 63;
    #pragma unroll
    for (int g=0; g<2; ++g){
      const int p = (tid>>6) + g*4;
      xout[(p0+p)*64 + o] = accf[o*8+p] / 10.f;
    }
  }
}

// ---------------- edge conv 3: graph_feature + W5 + mean (scalar, measured) ----------
__global__ __launch_bounds__(256) void edge3_k(const float* __restrict__ xin, const int* __restrict__ idx,
    const float* __restrict__ W5T,
    const float* __restrict__ s5, const float* __restrict__ t5,
    float* __restrict__ xout)
{
  const int lane = threadIdx.x & 63;
  const int pt = (blockIdx.x << 2) + (threadIdx.x >> 6);
  const int b = pt >> 12;
  float wd[64], wq[64];
  #pragma unroll
  for (int c=0;c<64;c++) wd[c] = W5T[c*64 + lane];
  #pragma unroll
  for (int c=0;c<64;c++) wq[c] = W5T[(64+c)*64 + lane];
  const float s5o=s5[lane], t5o=t5[lane];
  const float xq = xin[(size_t)pt*64 + lane];
  float a0=0.f,a1=0.f,a2=0.f,a3=0.f;
  #pragma unroll
  for (int c=0;c<64;c+=4){
    a0 += wq[c+0]*bc(xq,c+0);
    a1 += wq[c+1]*bc(xq,c+1);
    a2 += wq[c+2]*bc(xq,c+2);
    a3 += wq[c+3]*bc(xq,c+3);
  }
  const float yq = (a0+a1)+(a2+a3);
  const int* ip = idx + (size_t)pt*KK;
  float acc = 0.f;
  for (int j=0;j<KK;j++){
    const int ij = ip[j];
    const float xg = xin[((size_t)(b*NN + ij))*64 + lane];
    const float d = xg - xq;
    float p0=0.f,p1=0.f,p2=0.f,p3=0.f;
    #pragma unroll
    for (int c=0;c<64;c+=4){
      p0 += wd[c+0]*bc(d,c+0);
      p1 += wd[c+1]*bc(d,c+1);
      p2 += wd[c+2]*bc(d,c+2);
      p3 += wd[c+3]*bc(d,c+3);
    }
    acc += lrelu((yq + ((p0+p1)+(p2+p3)))*s5o + t5o);
  }
  xout[(size_t)pt*64 + lane] = acc / 10.f;
}

// ---------------- G1: h6 = lrelu(W6@z), accumulate sum over N ----------------
__global__ __launch_bounds__(256) void g1_k(const float* __restrict__ W6,
   const float* __restrict__ x1t, const float* __restrict__ x2t, const float* __restrict__ x3t,
   const float* __restrict__ s6, const float* __restrict__ t6, float* __restrict__ gsum)
{
  __shared__ float Wl[16*132];
  __shared__ float Zl[16*260];
  const int tid = threadIdx.x;
  const int rb = blockIdx.x & 1;
  const int nt = (blockIdx.x >> 1) & 15;
  const int b  = blockIdx.x >> 5;
  const int r0 = rb*128;
  const int n0 = nt*256;
  const int ty = tid >> 4, tx = tid & 15;
  float acc[8][16];
  #pragma unroll
  for (int i=0;i<8;i++){
    #pragma unroll
    for (int j=0;j<16;j++) acc[i][j] = 0.f;
  }
  for (int kc=0; kc<12; kc++){
    __syncthreads();
    {
      const int r = tid >> 1, h = tid & 1;
      const float4* wp = (const float4*)(W6 + (size_t)(r0 + r)*192 + kc*16 + h*8);
      float tmp[8];
      *(float4*)&tmp[0] = wp[0];
      *(float4*)&tmp[4] = wp[1];
      #pragma unroll
      for (int u=0;u<8;u++) Wl[(h*8+u)*132 + r] = tmp[u];
    }
    {
      const float* arr = (kc < 4) ? x1t : (kc < 8) ? x2t : x3t;
      const int chofs = (kc & 3)*16;
      const float4* zp = (const float4*)(arr + ((size_t)(b*NN) + n0 + tid)*64 + chofs);
      float tmp[16];
      *(float4*)&tmp[0]  = zp[0];
      *(float4*)&tmp[4]  = zp[1];
      *(float4*)&tmp[8]  = zp[2];
      *(float4*)&tmp[12] = zp[3];
      #pragma unroll
      for (int u=0;u<16;u++) Zl[u*260 + tid] = tmp[u];
    }
    __syncthreads();
    #pragma unroll 4
    for (int k=0;k<16;k++){
      float wv[8], zv[16];
      *(float4*)&wv[0] = *(const float4*)(&Wl[k*132 + ty*8]);
      *(float4*)&wv[4] = *(const float4*)(&Wl[k*132 + ty*8 + 4]);
      #pragma unroll
      for (int jg=0;jg<4;jg++)
        *(float4*)&zv[jg*4] = *(const float4*)(&Zl[k*260 + jg*64 + tx*4]);
      #pragma unroll
      for (int i=0;i<8;i++){
        #pragma unroll
        for (int j=0;j<16;j++) acc[i][j] += wv[i]*zv[j];
      }
    }
  }
  #pragma unroll
  for (int i=0;i<8;i++){
    const int row = r0 + ty*8 + i;
    const float sv = s6[row], tv = t6[row];
    float sum = 0.f;
    #pragma unroll
    for (int j=0;j<16;j++) sum += lrelu(acc[i][j]*sv + tv);
    #pragma unroll
    for (int d=1; d<16; d<<=1) sum += __shfl_xor(sum, d, 64);
    if ((tid & 15) == 0) atomicAdd(&gsum[b*256 + row], sum);
  }
}

// ---------------- G2: c7 = W7[:, :256] @ (gsum/4096) ----------------
__global__ __launch_bounds__(256) void g2_k(const float* __restrict__ W7,
   const float* __restrict__ gsum, float* __restrict__ c7)
{
  const int b = blockIdx.x >> 1;
  const int o = (blockIdx.x & 1)*256 + threadIdx.x;
  const float* wr = W7 + (size_t)o*448;
  const float* gb = gsum + b*256;
  float a0=0.f,a1=0.f,a2=0.f,a3=0.f;
  #pragma unroll 4
  for (int c=0;c<256;c+=4){
    a0 += wr[c+0]*gb[c+0]; a1 += wr[c+1]*gb[c+1];
    a2 += wr[c+2]*gb[c+2]; a3 += wr[c+3]*gb[c+3];
  }
  c7[b*512+o] = ((a0+a1)+(a2+a3)) * (1.f/4096.f);
}

// ---------------- G3: h7 = lrelu((W7[:,256:]@z + c7)) -> max/sum over N ----------------
__global__ __launch_bounds__(256) void g3_k(const float* __restrict__ W7,
   const float* __restrict__ x1t, const float* __restrict__ x2t, const float* __restrict__ x3t,
   const float* __restrict__ c7, const float* __restrict__ s7, const float* __restrict__ t7,
   unsigned* __restrict__ x4e, float* __restrict__ x5s)
{
  __shared__ float Wl[16*132];
  __shared__ float Zl[16*260];
  const int tid = threadIdx.x;
  const int rb = blockIdx.x & 3;
  const int nt = (blockIdx.x >> 2) & 15;
  const int b  = blockIdx.x >> 6;
  const int r0 = rb*128;
  const int n0 = nt*256;
  const int ty = tid >> 4, tx = tid & 15;
  float acc[8][16];
  #pragma unroll
  for (int i=0;i<8;i++){
    #pragma unroll
    for (int j=0;j<16;j++) acc[i][j] = 0.f;
  }
  for (int kc=0; kc<12; kc++){
    __syncthreads();
    {
      const int r = tid >> 1, h = tid & 1;
      const float4* wp = (const float4*)(W7 + (size_t)(r0 + r)*448 + 256 + kc*16 + h*8);
      float tmp[8];
      *(float4*)&tmp[0] = wp[0];
      *(float4*)&tmp[4] = wp[1];
      #pragma unroll
      for (int u=0;u<8;u++) Wl[(h*8+u)*132 + r] = tmp[u];
    }
    {
      const float* arr = (kc < 4) ? x1t : (kc < 8) ? x2t : x3t;
      const int chofs = (kc & 3)*16;
      const float4* zp = (const float4*)(arr + ((size_t)(b*NN) + n0 + tid)*64 + chofs);
      float tmp[16];
      *(float4*)&tmp[0]  = zp[0];
      *(float4*)&tmp[4]  = zp[1];
      *(float4*)&tmp[8]  = zp[2];
      *(float4*)&tmp[12] = zp[3];
      #pragma unroll
      for (int u=0;u<16;u++) Zl[u*260 + tid] = tmp[u];
    }
    __syncthreads();
    #pragma unroll 4
    for (int k=0;k<16;k++){
      float wv[8], zv[16];
      *(float4*)&wv[0] = *(const float4*)(&Wl[k*132 + ty*8]);
      *(float4*)&wv[4] = *(const float4*)(&Wl[k*132 + ty*8 + 4]);
      #pragma unroll
      for (int jg=0;jg<4;jg++)
        *(float4*)&zv[jg*4] = *(const float4*)(&Zl[k*260 + jg*64 + tx*4]);
      #pragma unroll
      for (int i=0;i<8;i++){
        #pragma unroll
        for (int j=0;j<16;j++) acc[i][j] += wv[i]*zv[j];
      }
    }
  }
  #pragma unroll
  for (int i=0;i<8;i++){
    const int row = r0 + ty*8 + i;
    const float c7v = c7[b*512 + row];
    const float sv = s7[row], tv = t7[row];
    float mx = -__builtin_inff(), sum = 0.f;
    #pragma unroll
    for (int j=0;j<16;j++){
      float h = lrelu((acc[i][j] + c7v)*sv + tv);
      mx = fmaxf(mx, h); sum += h;
    }
    #pragma unroll
    for (int d=1; d<16; d<<=1){
      sum += __shfl_xor(sum, d, 64);
      mx = fmaxf(mx, __shfl_xor(mx, d, 64));
    }
    if ((tid & 15) == 0){
      atomicAdd(&x5s[b*512 + row], sum);
      atomicMax(&x4e[b*512 + row], fenc(mx));
    }
  }
}

// ---------------- G4: final linear ----------------
__global__ __launch_bounds__(128) void g4_k(const float* __restrict__ W8T,
  const unsigned* __restrict__ x4e, const float* __restrict__ x5s,
  const float* __restrict__ s8, const float* __restrict__ t8, float* __restrict__ out)
{
  const int b = blockIdx.x, j = threadIdx.x;
  float a0 = 0.f, a1 = 0.f;
  for (int o=0;o<512;o++){
    a0 += W8T[o*128 + j] * fdec(x4e[b*512 + o]);
    a1 += W8T[(512+o)*128 + j] * (x5s[b*512 + o] * (1.f/4096.f));
  }
  const float y = a0 + a1;
  out[b*128 + j] = lrelu(y*s8[j] + t8[j]);
}

extern "C" void kernel_launch(void* const* d_in, const int* in_sizes, int n_in,
                              void* d_out, int out_size, void* d_ws, size_t ws_size,
                              hipStream_t stream) {
  (void)in_sizes; (void)n_in; (void)out_size; (void)ws_size;
  const float* x  = (const float*)d_in[0];
  const float* W1 = (const float*)d_in[1];
  const float* W2 = (const float*)d_in[2];
  const float* W3 = (const float*)d_in[3];
  const float* W4 = (const float*)d_in[4];
  const float* W5 = (const float*)d_in[5];
  const float* W6 = (const float*)d_in[6];
  const float* W7 = (const float*)d_in[7];
  const float* W8 = (const float*)d_in[8];
  const float* s1 = (const float*)d_in[9];   const float* t1 = (const float*)d_in[10];
  const float* s2 = (const float*)d_in[11];  const float* t2 = (const float*)d_in[12];
  const float* s3 = (const float*)d_in[13];  const float* t3 = (const float*)d_in[14];
  const float* s4 = (const float*)d_in[15];  const float* t4 = (const float*)d_in[16];
  const float* s5 = (const float*)d_in[17];  const float* t5 = (const float*)d_in[18];
  const float* s6 = (const float*)d_in[19];  const float* t6 = (const float*)d_in[20];
  const float* s7 = (const float*)d_in[21];  const float* t7 = (const float*)d_in[22];
  const float* s8 = (const float*)d_in[23];  const float* t8 = (const float*)d_in[24];

  char* wsb = (char*)d_ws;
  size_t off = 0;
  auto alloc = [&](size_t bytes)->char* {
    char* p = wsb + off;
    off += (bytes + 255) & ~(size_t)255;
    return p;
  };
  int*      idx1 = (int*)alloc((size_t)BB*NN*KK*4);
  int*      idx2 = (int*)alloc((size_t)BB*NN*KK*4);
  int*      idx3 = (int*)alloc((size_t)BB*NN*KK*4);
  u64*      pkeys= (u64*)alloc((size_t)BB*NN*4*KK*8);
  float*    x1t  = (float*)alloc((size_t)BB*NN*64*4);
  float*    x2t  = (float*)alloc((size_t)BB*NN*64*4);
  float*    x3t  = (float*)alloc((size_t)BB*NN*64*4);
  unsigned short* Xh = (unsigned short*)alloc((size_t)BB*NN*64*2);
  unsigned short* Xl = (unsigned short*)alloc((size_t)BB*NN*64*2);
  float*    xxb  = (float*)alloc((size_t)BB*NN*4);
  float*    gsum = (float*)alloc((size_t)BB*256*4);
  unsigned* x4e  = (unsigned*)alloc((size_t)BB*512*4);
  float*    x5s  = (float*)alloc((size_t)BB*512*4);
  float*    c7   = (float*)alloc((size_t)BB*512*4);
  float*    W1T  = (float*)alloc(14*64*4);
  float*    W2T  = (float*)alloc(64*64*4);
  float*    W5T  = (float*)alloc(128*64*4);
  float*    W8T  = (float*)alloc(1024*128*4);
  unsigned short* W3dh = (unsigned short*)alloc(64*64*2);
  unsigned short* W3dl = (unsigned short*)alloc(64*64*2);
  unsigned short* W3qh = (unsigned short*)alloc(64*64*2);
  unsigned short* W3ql = (unsigned short*)alloc(64*64*2);
  unsigned short* W4h  = (unsigned short*)alloc(64*64*2);
  unsigned short* W4l  = (unsigned short*)alloc(64*64*2);

  prep_k<<<64,256,0,stream>>>(W1,W2,W3,W4,W5,W8, W1T,W2T,W5T,W8T, W3dh,W3dl,W3qh,W3ql,W4h,W4l);
  knn2d_k<<<BB*64*4,256,0,stream>>>(x, pkeys);
  kmerge_k<<<BB*NN/256,256,0,stream>>>(pkeys, idx1);
  edge1_k<<<BB*NN/4,256,0,stream>>>(x, idx1, W1T, W2T, s1,t1,s2,t2, x1t);
  cvt_k<<<BB*NN*8/256,256,0,stream>>>(x1t, Xh, Xl, xxb);
  knn64_k<<<BB*64*4,256,0,stream>>>(Xh, Xl, xxb, pkeys);
  kmerge_k<<<BB*NN/256,256,0,stream>>>(pkeys, idx2);
  edge2_k<<<BB*NN/8,256,0,stream>>>(x1t, idx2, W3dh,W3dl,W3qh,W3ql,W4h,W4l, s3,t3,s4,t4, x2t);
  cvt_k<<<BB*NN*8/256,256,0,stream>>>(x2t, Xh, Xl, xxb);
  knn64_k<<<BB*64*4,256,0,stream>>>(Xh, Xl, xxb, pkeys);
  kmerge_k<<<BB*NN/256,256,0,stream>>>(pkeys, idx3);
  edge3_k<<<BB*NN/4,256,0,stream>>>(x2t, idx3, W5T, s5,t5, x3t);
  hipMemsetAsync(gsum, 0, (size_t)BB*256*4 + (size_t)BB*512*4*2, stream);
  g1_k<<<256,256,0,stream>>>(W6, x1t,x2t,x3t, s6,t6, gsum);
  g2_k<<<16,256,0,stream>>>(W7, gsum, c7);
  g3_k<<<512,256,0,stream>>>(W7, x1t,x2t,x3t, c7, s7,t7, x4e, x5s);
  g4_k<<<BB,128,0,stream>>>(W8T, x4e, x5s, s8,t8, (float*)d_out);
}

// Round 21
// 1038.381 us; speedup vs baseline: 1.1501x; 1.0175x over previous
//
#include <hip/hip_runtime.h>

#define BB 8
#define NN 4096
#define KK 10
#define CAP 24
#define TT 3
typedef unsigned long long u64;
typedef __attribute__((ext_vector_type(8))) short bf16x8;
typedef __attribute__((ext_vector_type(4))) float f32x4;

__device__ __forceinline__ float lrelu(float v){ return v >= 0.f ? v : 0.2f*v; }
__device__ __forceinline__ float bc(float v, int l){
  return __int_as_float(__builtin_amdgcn_readlane(__float_as_int(v), l));
}
__device__ __forceinline__ unsigned fenc(float f){
  unsigned u = __float_as_uint(f);
  return u ^ (((unsigned)((int)u >> 31)) | 0x80000000u);
}
__device__ __forceinline__ float fdec(unsigned e){
  return (e & 0x80000000u) ? __uint_as_float(e & 0x7fffffffu) : __uint_as_float(~e);
}

// ---------------- weight prep: transposes + split-bf16 conversions ----------------
__global__ __launch_bounds__(256) void prep_k(
    const float* __restrict__ W1, const float* __restrict__ W2, const float* __restrict__ W3,
    const float* __restrict__ W4, const float* __restrict__ W5, const float* __restrict__ W8,
    float* __restrict__ W1T, float* __restrict__ W2T, float* __restrict__ W5T, float* __restrict__ W8T,
    unsigned short* __restrict__ W3dh, unsigned short* __restrict__ W3dl,
    unsigned short* __restrict__ W3qh, unsigned short* __restrict__ W3ql,
    unsigned short* __restrict__ W4h,  unsigned short* __restrict__ W4l)
{
  const int t = blockIdx.x*256 + threadIdx.x;
  const int stride = gridDim.x*256;
  for (int i=t; i<64*14; i+=stride){ int o=i/14, c=i%14; W1T[c*64+o]=W1[i]; }
  for (int i=t; i<64*64; i+=stride){ int o=i>>6, c=i&63; W2T[c*64+o]=W2[i]; }
  for (int i=t; i<64*128; i+=stride){ int o=i>>7, c=i&127; W5T[c*64+o]=W5[i]; }
  for (int i=t; i<128*1024; i+=stride){ int o=i>>10, c=i&1023; W8T[c*128+o]=W8[i]; }
  for (int i=t; i<64*64; i+=stride){
    int o=i>>6, c=i&63;
    float f = W3[o*128 + c];
    unsigned u = __float_as_uint(f);
    W3dh[i] = (unsigned short)(u >> 16);
    float lo = f - __uint_as_float(u & 0xffff0000u);
    W3dl[i] = (unsigned short)(__float_as_uint(lo) >> 16);
  }
  for (int i=t; i<64*64; i+=stride){
    int o=i>>6, c=i&63;
    float f = W3[o*128 + 64 + c];
    unsigned u = __float_as_uint(f);
    W3qh[i] = (unsigned short)(u >> 16);
    float lo = f - __uint_as_float(u & 0xffff0000u);
    W3ql[i] = (unsigned short)(__float_as_uint(lo) >> 16);
  }
  for (int i=t; i<64*64; i+=stride){
    float f = W4[i];
    unsigned u = __float_as_uint(f);
    W4h[i] = (unsigned short)(u >> 16);
    float lo = f - __uint_as_float(u & 0xffff0000u);
    W4l[i] = (unsigned short)(__float_as_uint(lo) >> 16);
  }
}

// ---------------- one-time fp32 -> split bf16 (hi/lo) + squared norms ----------------
__global__ __launch_bounds__(256) void cvt_k(const float* __restrict__ xin,
    unsigned short* __restrict__ Xh, unsigned short* __restrict__ Xl, float* __restrict__ xx)
{
  const int gid = blockIdx.x*256 + threadIdx.x;   // BB*NN*8 threads
  const int p = gid >> 3, c8 = (gid & 7) << 3;
  const float* src = xin + (size_t)p*64 + c8;
  float fv[8];
  *(float4*)&fv[0] = *(const float4*)(src);
  *(float4*)&fv[4] = *(const float4*)(src + 4);
  unsigned hp[4], lp[4];
  float ssq = 0.f;
  #pragma unroll
  for (int e=0; e<4; e++){
    float f0 = fv[2*e], f1 = fv[2*e+1];
    ssq += f0*f0 + f1*f1;
    unsigned u0 = __float_as_uint(f0), u1 = __float_as_uint(f1);
    hp[e] = (u0 >> 16) | (u1 & 0xffff0000u);
    float l0 = f0 - __uint_as_float(u0 & 0xffff0000u);
    float l1 = f1 - __uint_as_float(u1 & 0xffff0000u);
    lp[e] = (__float_as_uint(l0) >> 16) | (__float_as_uint(l1) & 0xffff0000u);
  }
  *(uint4*)(Xh + (size_t)p*64 + c8) = uint4{hp[0],hp[1],hp[2],hp[3]};
  *(uint4*)(Xl + (size_t)p*64 + c8) = uint4{lp[0],lp[1],lp[2],lp[3]};
  ssq += __shfl_xor(ssq, 1, 64);
  ssq += __shfl_xor(ssq, 2, 64);
  ssq += __shfl_xor(ssq, 4, 64);
  if ((gid & 7) == 0) xx[p] = ssq;
}

// ---------------- knn over first 2 channels: two-phase selection (top-TT) ----------
__global__ __launch_bounds__(256) void knn2d_k(const float* __restrict__ x, u64* __restrict__ pk)
{
  __shared__ float px[1024], py[1024], pxx[1024];
  __shared__ unsigned cnt[64];
  __shared__ u64 lst[CAP][64];
  const int tid = threadIdx.x;
  const int b  = blockIdx.x >> 8;
  const int qt = (blockIdx.x >> 2) & 63;
  const int h  = blockIdx.x & 3;
  const int q0 = qt*64;
  const int m0g = h*1024;
  const float* xb = x + (size_t)b*7*NN;
  for (int m = tid; m < 1024; m += 256){
    float a = xb[m0g + m], c = xb[NN + m0g + m];
    px[m] = a; py[m] = c; pxx[m] = a*a + c*c;
  }
  if (tid < 64) cnt[tid] = 0;
  __syncthreads();

  const int ty = tid >> 4, tx = tid & 15;
  const int qr = ty*4;
  float qx4[4], qy4[4], q24[4];
  #pragma unroll
  for (int i=0;i<4;i++){
    float a = xb[q0+qr+i], c = xb[NN + q0+qr+i];
    qx4[i] = a; qy4[i] = c; q24[i] = a*a + c*c;
  }

  float bv[4][TT];
  #pragma unroll
  for (int i=0;i<4;i++){
    #pragma unroll
    for (int s=0;s<TT;s++) bv[i][s] = -__builtin_inff();
  }

  for (int ot=0; ot<8; ot++){
    #pragma unroll
    for (int j=0;j<8;j++){
      const int ml = ot*128 + j*16 + tx;
      const float cmx = px[ml], cmy = py[ml], cm2 = pxx[ml];
      #pragma unroll
      for (int i=0;i<4;i++){
        float dot = qx4[i]*cmx + qy4[i]*cmy;
        float v = (-q24[i]) - (-2.f*dot) - cm2;
        float c = v;
        #pragma unroll
        for (int s=0;s<TT;s++){
          float nb = fmaxf(bv[i][s], c);
          c = fminf(bv[i][s], c);
          bv[i][s] = nb;
        }
      }
    }
  }

  float thr[4];
  #pragma unroll
  for (int i=0;i<4;i++){
    float m = 0.f;
    #pragma unroll
    for (int k=0;k<10;k++){
      float hh = bv[i][0];
      m = hh;
      m = fmaxf(m, __shfl_xor(m, 1, 64));
      m = fmaxf(m, __shfl_xor(m, 2, 64));
      m = fmaxf(m, __shfl_xor(m, 4, 64));
      m = fmaxf(m, __shfl_xor(m, 8, 64));
      if (k < 9){
        if (hh == m){
          #pragma unroll
          for (int s=0;s<TT-1;s++) bv[i][s] = bv[i][s+1];
          bv[i][TT-1] = -__builtin_inff();
        }
      }
    }
    thr[i] = m;
  }

  for (int ot=0; ot<8; ot++){
    #pragma unroll
    for (int j=0;j<8;j++){
      const int ml = ot*128 + j*16 + tx;
      const float cmx = px[ml], cmy = py[ml], cm2 = pxx[ml];
      const unsigned mk = ~(unsigned)(m0g + ml);
      #pragma unroll
      for (int i=0;i<4;i++){
        float dot = qx4[i]*cmx + qy4[i]*cmy;
        float v = (-q24[i]) - (-2.f*dot) - cm2;
        if (v >= thr[i]){
          u64 key = ((u64)fenc(v) << 32) | mk;
          const int r = qr + i;
          unsigned slot = atomicAdd(&cnt[r], 1u);
          if (slot < CAP) lst[slot][r] = key;
        }
      }
    }
  }
  __syncthreads();

  if (tid < 64){
    int n = (int)cnt[tid]; if (n > CAP) n = CAP;
    u64* op = pk + (((size_t)b*NN + q0 + tid)*4 + h)*KK;
    for (int k=0;k<KK;k++){
      u64 best = 0ull; int bi = 0;
      for (int s=0;s<n;s++){
        u64 v2 = lst[s][tid];
        if (v2 > best){ best = v2; bi = s; }
      }
      if (best) lst[bi][tid] = 0ull;
      op[k] = best;
    }
  }
}

// ---------------- knn over 64 channels: two-phase + async-STAGE split (T14) --------
__global__ __launch_bounds__(256) void knn64_k(const unsigned short* __restrict__ Xh,
    const unsigned short* __restrict__ Xl, const float* __restrict__ xx, u64* __restrict__ pk)
{
  __shared__ unsigned short Ch[64*72], Cl[64*72];
  __shared__ float cxx[64];
  __shared__ unsigned cnt[64];
  __shared__ u64 lst[CAP][64];
  const int tid = threadIdx.x;
  const int b  = blockIdx.x >> 8;
  const int qt = (blockIdx.x >> 2) & 63;
  const int h  = blockIdx.x & 3;
  const int q0 = qt*64;
  const int m0g = h*1024;
  const unsigned short* Xhb = Xh + (size_t)b*NN*64;
  const unsigned short* Xlb = Xl + (size_t)b*NN*64;
  const float* xxb = xx + (size_t)b*NN;

  const int sp = tid >> 2;
  const int sc = (tid & 3) << 4;

  const int lane = tid & 63;
  const int w    = tid >> 6;
  const int col  = lane & 15;
  const int quad = (tid >> 4) & 3;
  const int qr   = (tid >> 4)*4;

  const size_t abase = (size_t)(q0 + w*16 + col)*64 + quad*8;
  bf16x8 Ah0 = *(const bf16x8*)(Xhb + abase);
  bf16x8 Ah1 = *(const bf16x8*)(Xhb + abase + 32);
  bf16x8 Al0 = *(const bf16x8*)(Xlb + abase);
  bf16x8 Al1 = *(const bf16x8*)(Xlb + abase + 32);

  float qx4[4];
  #pragma unroll
  for (int i=0;i<4;i++) qx4[i] = xxb[q0 + qr + i];

  if (tid < 64) cnt[tid] = 0;

  float bv[4][TT];
  #pragma unroll
  for (int i=0;i<4;i++){
    #pragma unroll
    for (int s=0;s<TT;s++) bv[i][s] = -__builtin_inff();
  }

  uint4 rh0, rh1, rl0, rl1;
  float cxv = 0.f;
  {
    const uint4* sh = (const uint4*)(Xhb + (size_t)(m0g+sp)*64 + sc);
    const uint4* sl = (const uint4*)(Xlb + (size_t)(m0g+sp)*64 + sc);
    rh0 = sh[0]; rh1 = sh[1]; rl0 = sl[0]; rl1 = sl[1];
    if (tid < 64) cxv = xxb[m0g + tid];
  }

  // ================= phase 1: values only =================
  for (int ct=0; ct<16; ct++){
    __syncthreads();
    *(uint4*)(&Ch[sp*72 + sc])     = rh0;
    *(uint4*)(&Ch[sp*72 + sc + 8]) = rh1;
    *(uint4*)(&Cl[sp*72 + sc])     = rl0;
    *(uint4*)(&Cl[sp*72 + sc + 8]) = rl1;
    if (tid < 64) cxx[tid] = cxv;
    if (ct < 15){
      const int mn = m0g + (ct+1)*64;
      const uint4* sh = (const uint4*)(Xhb + (size_t)(mn+sp)*64 + sc);
      const uint4* sl = (const uint4*)(Xlb + (size_t)(mn+sp)*64 + sc);
      rh0 = sh[0]; rh1 = sh[1]; rl0 = sl[0]; rl1 = sl[1];
      if (tid < 64) cxv = xxb[mn + tid];
    }
    __syncthreads();

    #pragma unroll
    for (int j=0;j<4;j++){
      const int boff = (j*16 + col)*72 + quad*8;
      bf16x8 Bh0 = *(const bf16x8*)(&Ch[boff]);
      bf16x8 Bh1 = *(const bf16x8*)(&Ch[boff+32]);
      bf16x8 Bl0 = *(const bf16x8*)(&Cl[boff]);
      bf16x8 Bl1 = *(const bf16x8*)(&Cl[boff+32]);
      f32x4 d = {0.f,0.f,0.f,0.f};
      d = __builtin_amdgcn_mfma_f32_16x16x32_bf16(Al0, Bh0, d, 0,0,0);
      d = __builtin_amdgcn_mfma_f32_16x16x32_bf16(Ah0, Bl0, d, 0,0,0);
      d = __builtin_amdgcn_mfma_f32_16x16x32_bf16(Ah0, Bh0, d, 0,0,0);
      d = __builtin_amdgcn_mfma_f32_16x16x32_bf16(Al1, Bh1, d, 0,0,0);
      d = __builtin_amdgcn_mfma_f32_16x16x32_bf16(Ah1, Bl1, d, 0,0,0);
      d = __builtin_amdgcn_mfma_f32_16x16x32_bf16(Ah1, Bh1, d, 0,0,0);

      const float cx = cxx[j*16 + col];
      #pragma unroll
      for (int i=0;i<4;i++){
        float v = (-qx4[i]) - (-2.f*d[i]) - cx;
        float c = v;
        #pragma unroll
        for (int s=0;s<TT;s++){
          float nb = fmaxf(bv[i][s], c);
          c = fminf(bv[i][s], c);
          bv[i][s] = nb;
        }
      }
    }
  }

  // issue phase-2 tile-0 loads; they overlap the pop-merge below
  {
    const uint4* sh = (const uint4*)(Xhb + (size_t)(m0g+sp)*64 + sc);
    const uint4* sl = (const uint4*)(Xlb + (size_t)(m0g+sp)*64 + sc);
    rh0 = sh[0]; rh1 = sh[1]; rl0 = sl[0]; rl1 = sl[1];
    if (tid < 64) cxv = xxb[m0g + tid];
  }

  // ================= row 10th value (16-lane pop-merge) =================
  float thr[4];
  #pragma unroll
  for (int i=0;i<4;i++){
    float m = 0.f;
    #pragma unroll
    for (int k=0;k<10;k++){
      float hh = bv[i][0];
      m = hh;
      m = fmaxf(m, __shfl_xor(m, 1, 64));
      m = fmaxf(m, __shfl_xor(m, 2, 64));
      m = fmaxf(m, __shfl_xor(m, 4, 64));
      m = fmaxf(m, __shfl_xor(m, 8, 64));
      if (k < 9){
        if (hh == m){
          #pragma unroll
          for (int s=0;s<TT-1;s++) bv[i][s] = bv[i][s+1];
          bv[i][TT-1] = -__builtin_inff();
        }
      }
    }
    thr[i] = m;
  }

  // ================= phase 2: exact collection =================
  for (int ct=0; ct<16; ct++){
    __syncthreads();
    *(uint4*)(&Ch[sp*72 + sc])     = rh0;
    *(uint4*)(&Ch[sp*72 + sc + 8]) = rh1;
    *(uint4*)(&Cl[sp*72 + sc])     = rl0;
    *(uint4*)(&Cl[sp*72 + sc + 8]) = rl1;
    if (tid < 64) cxx[tid] = cxv;
    if (ct < 15){
      const int mn = m0g + (ct+1)*64;
      const uint4* sh = (const uint4*)(Xhb + (size_t)(mn+sp)*64 + sc);
      const uint4* sl = (const uint4*)(Xlb + (size_t)(mn+sp)*64 + sc);
      rh0 = sh[0]; rh1 = sh[1]; rl0 = sl[0]; rl1 = sl[1];
      if (tid < 64) cxv = xxb[mn + tid];
    }
    __syncthreads();

    const int m0 = m0g + ct*64;
    #pragma unroll
    for (int j=0;j<4;j++){
      const int boff = (j*16 + col)*72 + quad*8;
      bf16x8 Bh0 = *(const bf16x8*)(&Ch[boff]);
      bf16x8 Bh1 = *(const bf16x8*)(&Ch[boff+32]);
      bf16x8 Bl0 = *(const bf16x8*)(&Cl[boff]);
      bf16x8 Bl1 = *(const bf16x8*)(&Cl[boff+32]);
      f32x4 d = {0.f,0.f,0.f,0.f};
      d = __builtin_amdgcn_mfma_f32_16x16x32_bf16(Al0, Bh0, d, 0,0,0);
      d = __builtin_amdgcn_mfma_f32_16x16x32_bf16(Ah0, Bl0, d, 0,0,0);
      d = __builtin_amdgcn_mfma_f32_16x16x32_bf16(Ah0, Bh0, d, 0,0,0);
      d = __builtin_amdgcn_mfma_f32_16x16x32_bf16(Al1, Bh1, d, 0,0,0);
      d = __builtin_amdgcn_mfma_f32_16x16x32_bf16(Ah1, Bl1, d, 0,0,0);
      d = __builtin_amdgcn_mfma_f32_16x16x32_bf16(Ah1, Bh1, d, 0,0,0);

      const int m = m0 + j*16 + col;
      const float cx = cxx[j*16 + col];
      const unsigned mk = ~(unsigned)m;
      #pragma unroll
      for (int i=0;i<4;i++){
        float v = (-qx4[i]) - (-2.f*d[i]) - cx;
        if (v >= thr[i]){
          u64 key = ((u64)fenc(v) << 32) | mk;
          const int r = qr + i;
          unsigned slot = atomicAdd(&cnt[r], 1u);
          if (slot < CAP) lst[slot][r] = key;
        }
      }
    }
  }
  __syncthreads();

  if (tid < 64){
    int n = (int)cnt[tid]; if (n > CAP) n = CAP;
    u64* op = pk + (((size_t)b*NN + q0 + tid)*4 + h)*KK;
    for (int k=0;k<KK;k++){
      u64 best = 0ull; int bi = 0;
      for (int s=0;s<n;s++){
        u64 v2 = lst[s][tid];
        if (v2 > best){ best = v2; bi = s; }
      }
      if (best) lst[bi][tid] = 0ull;
      op[k] = best;
    }
  }
}

// ---------------- merge four sorted-desc 10-key quarters -> final idx ----------------
__global__ __launch_bounds__(256) void kmerge_k(const u64* __restrict__ pk, int* __restrict__ idxo)
{
  const int q = blockIdx.x*256 + threadIdx.x;   // q < BB*NN
  const u64* A = pk + (size_t)q*(4*KK);
  int* op = idxo + (size_t)q*KK;
  int ia = 0, ib = 0, ic = 0, id = 0;
  #pragma unroll
  for (int k=0;k<KK;k++){
    u64 a  = (ia < KK) ? A[ia]        : 0ull;
    u64 b2 = (ib < KK) ? A[KK + ib]   : 0ull;
    u64 c2 = (ic < KK) ? A[2*KK + ic] : 0ull;
    u64 d2 = (id < KK) ? A[3*KK + id] : 0ull;
    u64 m1 = a >= b2 ? a : b2;  int s1 = a >= b2 ? 0 : 1;
    u64 m2 = c2 >= d2 ? c2 : d2; int s2 = c2 >= d2 ? 2 : 3;
    u64 mm = m1 >= m2 ? m1 : m2; int ss = m1 >= m2 ? s1 : s2;
    op[k] = (int)(~(unsigned)mm);
    if (ss == 0) ia++; else if (ss == 1) ib++; else if (ss == 2) ic++; else id++;
  }
}

// ---------------- edge conv 1: graph_feature1 + W1 + W2 + mean (scalar, measured) ----
__global__ __launch_bounds__(256) void edge1_k(const float* __restrict__ x, const int* __restrict__ idx,
    const float* __restrict__ W1T, const float* __restrict__ W2T,
    const float* __restrict__ s1, const float* __restrict__ t1,
    const float* __restrict__ s2, const float* __restrict__ t2,
    float* __restrict__ x1t)
{
  const int lane = threadIdx.x & 63;
  const int pt = (blockIdx.x << 2) + (threadIdx.x >> 6);
  const int b = pt >> 12, n = pt & 4095;
  const float* xb = x + (size_t)b*7*NN;
  float w1r[14], w2r[64];
  #pragma unroll
  for (int c=0;c<14;c++) w1r[c] = W1T[c*64 + lane];
  #pragma unroll
  for (int c=0;c<64;c++) w2r[c] = W2T[c*64 + lane];
  const float s1o=s1[lane], t1o=t1[lane], s2o=s2[lane], t2o=t2[lane];
  const float xq = (lane < 7) ? xb[lane*NN + n] : 0.f;
  const float xq0 = bc(xq,0), xq1 = bc(xq,1);
  float qy1 = 0.f;
  #pragma unroll
  for (int c=0;c<7;c++) qy1 += w1r[7+c]*bc(xq,c);
  const int* ip = idx + (size_t)pt*KK;
  float acc = 0.f;
  for (int j=0;j<KK;j++){
    const int ij = ip[j];
    const float xg = (lane < 7) ? xb[lane*NN + ij] : 0.f;
    float y1 = qy1;
    y1 += w1r[0]*(bc(xg,0) - xq0);
    y1 += w1r[1]*(bc(xg,1) - xq1);
    #pragma unroll
    for (int c=2;c<7;c++) y1 += w1r[c]*bc(xg,c);
    const float z1 = lrelu(y1*s1o + t1o);
    float p0=0.f,p1=0.f,p2=0.f,p3=0.f;
    #pragma unroll
    for (int c=0;c<64;c+=4){
      p0 += w2r[c+0]*bc(z1,c+0);
      p1 += w2r[c+1]*bc(z1,c+1);
      p2 += w2r[c+2]*bc(z1,c+2);
      p3 += w2r[c+3]*bc(z1,c+3);
    }
    acc += lrelu(((p0+p1)+(p2+p3))*s2o + t2o);
  }
  x1t[(size_t)pt*64 + lane] = acc / 10.f;
}

// ---------------- edge conv 2: MFMA split-bf16 (GEMM1: W3d@d + W3q@xq, GEMM2: W4@z3) --
__global__ __launch_bounds__(256) void edge2_k(const float* __restrict__ x1t, const int* __restrict__ idx,
    const unsigned short* __restrict__ W3dh, const unsigned short* __restrict__ W3dl,
    const unsigned short* __restrict__ W3qh, const unsigned short* __restrict__ W3ql,
    const unsigned short* __restrict__ W4h,  const unsigned short* __restrict__ W4l,
    const float* __restrict__ s3, const float* __restrict__ t3,
    const float* __restrict__ s4, const float* __restrict__ t4,
    float* __restrict__ xout)
{
  __shared__ unsigned short Zh[80*72], Zl[80*72];   // D staging -> z3 overlay
  __shared__ unsigned short Qh[16*72], Ql[16*72];
  __shared__ float accf[64*8];
  const int tid = threadIdx.x;
  const size_t p0 = (size_t)blockIdx.x * 8;

  ((float2*)accf)[tid] = float2{0.f, 0.f};

  #pragma unroll
  for (int pass=0; pass<2; ++pass){
    const int col = pass*64 + (tid>>2);
    const int sc16 = (tid&3)*16;
    if (col < 88){
      float dv[16];
      if (col < 80){
        const int p = col/10, j = col - p*10;
        const size_t pt = p0 + p;
        const int bb = (int)(pt >> 12);
        const int ij = idx[pt*KK + j];
        const float* gs = x1t + ((size_t)bb*NN + ij)*64 + sc16;
        const float* qs = x1t + pt*64 + sc16;
        #pragma unroll
        for (int e=0;e<4;e++){
          float4 g4 = *(const float4*)(gs + e*4);
          float4 q4 = *(const float4*)(qs + e*4);
          dv[e*4+0]=g4.x-q4.x; dv[e*4+1]=g4.y-q4.y; dv[e*4+2]=g4.z-q4.z; dv[e*4+3]=g4.w-q4.w;
        }
      } else {
        const int cl = col - 80;
        const float* qs = x1t + (size_t)(p0+cl)*64 + sc16;
        #pragma unroll
        for (int e=0;e<4;e++){
          float4 q4 = *(const float4*)(qs + e*4);
          dv[e*4+0]=q4.x; dv[e*4+1]=q4.y; dv[e*4+2]=q4.z; dv[e*4+3]=q4.w;
        }
      }
      unsigned hp[8], lp[8];
      #pragma unroll
      for (int e=0;e<8;e++){
        float f0 = dv[2*e], f1 = dv[2*e+1];
        unsigned u0 = __float_as_uint(f0), u1 = __float_as_uint(f1);
        hp[e] = (u0 >> 16) | (u1 & 0xffff0000u);
        float l0 = f0 - __uint_as_float(u0 & 0xffff0000u);
        float l1 = f1 - __uint_as_float(u1 & 0xffff0000u);
        lp[e] = (__float_as_uint(l0) >> 16) | (__float_as_uint(l1) & 0xffff0000u);
      }
      if (col < 80){
        *(uint4*)(&Zh[col*72 + sc16])     = uint4{hp[0],hp[1],hp[2],hp[3]};
        *(uint4*)(&Zh[col*72 + sc16 + 8]) = uint4{hp[4],hp[5],hp[6],hp[7]};
        *(uint4*)(&Zl[col*72 + sc16])     = uint4{lp[0],lp[1],lp[2],lp[3]};
        *(uint4*)(&Zl[col*72 + sc16 + 8]) = uint4{lp[4],lp[5],lp[6],lp[7]};
      } else {
        const int cl = col - 80;
        *(uint4*)(&Qh[cl*72 + sc16])     = uint4{hp[0],hp[1],hp[2],hp[3]};
        *(uint4*)(&Qh[cl*72 + sc16 + 8]) = uint4{hp[4],hp[5],hp[6],hp[7]};
        *(uint4*)(&Ql[cl*72 + sc16])     = uint4{lp[0],lp[1],lp[2],lp[3]};
        *(uint4*)(&Ql[cl*72 + sc16 + 8]) = uint4{lp[4],lp[5],lp[6],lp[7]};
      }
    } else if (col < 96){
      const int cl = col - 80;
      const uint4 z{0u,0u,0u,0u};
      *(uint4*)(&Qh[cl*72 + sc16])     = z;
      *(uint4*)(&Qh[cl*72 + sc16 + 8]) = z;
      *(uint4*)(&Ql[cl*72 + sc16])     = z;
      *(uint4*)(&Ql[cl*72 + sc16 + 8]) = z;
    }
  }
  __syncthreads();

  const int lane = tid & 63;
  const int w    = tid >> 6;
  const int colL = lane & 15;
  const int quad = lane >> 4;
  const int arow = (w*16 + colL)*64 + quad*8;

  bf16x8 Adh0 = *(const bf16x8*)(W3dh + arow);
  bf16x8 Adh1 = *(const bf16x8*)(W3dh + arow + 32);
  bf16x8 Adl0 = *(const bf16x8*)(W3dl + arow);
  bf16x8 Adl1 = *(const bf16x8*)(W3dl + arow + 32);

  f32x4 C1[5];
  #pragma unroll
  for (int t=0;t<5;t++){
    const int boff = (t*16 + colL)*72 + quad*8;
    bf16x8 Bh0 = *(const bf16x8*)(&Zh[boff]);
    bf16x8 Bh1 = *(const bf16x8*)(&Zh[boff+32]);
    bf16x8 Bl0 = *(const bf16x8*)(&Zl[boff]);
    bf16x8 Bl1 = *(const bf16x8*)(&Zl[boff+32]);
    f32x4 d = {0.f,0.f,0.f,0.f};
    d = __builtin_amdgcn_mfma_f32_16x16x32_bf16(Adl0, Bh0, d, 0,0,0);
    d = __builtin_amdgcn_mfma_f32_16x16x32_bf16(Adh0, Bl0, d, 0,0,0);
    d = __builtin_amdgcn_mfma_f32_16x16x32_bf16(Adh0, Bh0, d, 0,0,0);
    d = __builtin_amdgcn_mfma_f32_16x16x32_bf16(Adl1, Bh1, d, 0,0,0);
    d = __builtin_amdgcn_mfma_f32_16x16x32_bf16(Adh1, Bl1, d, 0,0,0);
    d = __builtin_amdgcn_mfma_f32_16x16x32_bf16(Adh1, Bh1, d, 0,0,0);
    C1[t] = d;
  }
  f32x4 Cu;
  {
    bf16x8 Aqh0 = *(const bf16x8*)(W3qh + arow);
    bf16x8 Aqh1 = *(const bf16x8*)(W3qh + arow + 32);
    bf16x8 Aql0 = *(const bf16x8*)(W3ql + arow);
    bf16x8 Aql1 = *(const bf16x8*)(W3ql + arow + 32);
    const int boff = colL*72 + quad*8;
    bf16x8 Bh0 = *(const bf16x8*)(&Qh[boff]);
    bf16x8 Bh1 = *(const bf16x8*)(&Qh[boff+32]);
    bf16x8 Bl0 = *(const bf16x8*)(&Ql[boff]);
    bf16x8 Bl1 = *(const bf16x8*)(&Ql[boff+32]);
    f32x4 d = {0.f,0.f,0.f,0.f};
    d = __builtin_amdgcn_mfma_f32_16x16x32_bf16(Aql0, Bh0, d, 0,0,0);
    d = __builtin_amdgcn_mfma_f32_16x16x32_bf16(Aqh0, Bl0, d, 0,0,0);
    d = __builtin_amdgcn_mfma_f32_16x16x32_bf16(Aqh0, Bh0, d, 0,0,0);
    d = __builtin_amdgcn_mfma_f32_16x16x32_bf16(Aql1, Bh1, d, 0,0,0);
    d = __builtin_amdgcn_mfma_f32_16x16x32_bf16(Aqh1, Bl1, d, 0,0,0);
    d = __builtin_amdgcn_mfma_f32_16x16x32_bf16(Aqh1, Bh1, d, 0,0,0);
    Cu = d;
  }

  float s3v[4], t3v[4], s4v[4], t4v[4];
  #pragma unroll
  for (int i=0;i<4;i++){
    const int o = w*16 + quad*4 + i;
    s3v[i]=s3[o]; t3v[i]=t3[o]; s4v[i]=s4[o]; t4v[i]=t4[o];
  }

  __syncthreads();

  #pragma unroll
  for (int t=0;t<5;t++){
    const int gc = t*16 + colL;
    const int p  = gc/10;
    const int srcb = (((lane & 48) | p) << 2);
    float z[4];
    #pragma unroll
    for (int i=0;i<4;i++){
      float ui = __int_as_float(__builtin_amdgcn_ds_bpermute(srcb, __float_as_int(Cu[i])));
      float zp = (C1[t][i] + ui)*s3v[i] + t3v[i];
      z[i] = zp >= 0.f ? zp : 0.2f*zp;
    }
    unsigned u0=__float_as_uint(z[0]), u1=__float_as_uint(z[1]);
    unsigned u2=__float_as_uint(z[2]), u3=__float_as_uint(z[3]);
    unsigned h01 = (u0>>16) | (u1 & 0xffff0000u);
    unsigned h23 = (u2>>16) | (u3 & 0xffff0000u);
    float l0 = z[0]-__uint_as_float(u0&0xffff0000u);
    float l1 = z[1]-__uint_as_float(u1&0xffff0000u);
    float l2 = z[2]-__uint_as_float(u2&0xffff0000u);
    float l3 = z[3]-__uint_as_float(u3&0xffff0000u);
    unsigned l01 = (__float_as_uint(l0)>>16) | (__float_as_uint(l1)&0xffff0000u);
    unsigned l23 = (__float_as_uint(l2)>>16) | (__float_as_uint(l3)&0xffff0000u);
    const int rb = w*16 + quad*4;
    *(uint2*)(&Zh[gc*72 + rb]) = uint2{h01,h23};
    *(uint2*)(&Zl[gc*72 + rb]) = uint2{l01,l23};
  }
  __syncthreads();

  bf16x8 A4h0 = *(const bf16x8*)(W4h + arow);
  bf16x8 A4h1 = *(const bf16x8*)(W4h + arow + 32);
  bf16x8 A4l0 = *(const bf16x8*)(W4l + arow);
  bf16x8 A4l1 = *(const bf16x8*)(W4l + arow + 32);
  #pragma unroll
  for (int t=0;t<5;t++){
    const int boff = (t*16 + colL)*72 + quad*8;
    bf16x8 Bh0 = *(const bf16x8*)(&Zh[boff]);
    bf16x8 Bh1 = *(const bf16x8*)(&Zh[boff+32]);
    bf16x8 Bl0 = *(const bf16x8*)(&Zl[boff]);
    bf16x8 Bl1 = *(const bf16x8*)(&Zl[boff+32]);
    f32x4 d = {0.f,0.f,0.f,0.f};
    d = __builtin_amdgcn_mfma_f32_16x16x32_bf16(A4l0, Bh0, d, 0,0,0);
    d = __builtin_amdgcn_mfma_f32_16x16x32_bf16(A4h0, Bl0, d, 0,0,0);
    d = __builtin_amdgcn_mfma_f32_16x16x32_bf16(A4h0, Bh0, d, 0,0,0);
    d = __builtin_amdgcn_mfma_f32_16x16x32_bf16(A4l1, Bh1, d, 0,0,0);
    d = __builtin_amdgcn_mfma_f32_16x16x32_bf16(A4h1, Bl1, d, 0,0,0);
    d = __builtin_amdgcn_mfma_f32_16x16x32_bf16(A4h1, Bh1, d, 0,0,0);
    const int gc = t*16 + colL;
    const int p  = gc/10;
    #pragma unroll
    for (int i=0;i<4;i++){
      float v = d[i]*s4v[i] + t4v[i];
      v = v >= 0.f ? v : 0.2f*v;
      atomicAdd(&accf[(w*16 + quad*4 + i)*8 + p], v);
    }
  }
  __syncthreads();

  {
    const int o = tid & 63;
    #pragma unroll
    for (int g=0; g<2; ++g){
      const int p = (tid>>6) + g*4;
      xout[(p0+p)*64 + o] = accf[o*8+p] / 10.f;
    }
  }
}

// ---------------- edge conv 3: graph_feature + W5 + mean (scalar, measured) ----------
__global__ __launch_bounds__(256) void edge3_k(const float* __restrict__ xin, const int* __restrict__ idx,
    const float* __restrict__ W5T,
    const float* __restrict__ s5, const float* __restrict__ t5,
    float* __restrict__ xout)
{
  const int lane = threadIdx.x & 63;
  const int pt = (blockIdx.x << 2) + (threadIdx.x >> 6);
  const int b = pt >> 12;
  float wd[64], wq[64];
  #pragma unroll
  for (int c=0;c<64;c++) wd[c] = W5T[c*64 + lane];
  #pragma unroll
  for (int c=0;c<64;c++) wq[c] = W5T[(64+c)*64 + lane];
  const float s5o=s5[lane], t5o=t5[lane];
  const float xq = xin[(size_t)pt*64 + lane];
  float a0=0.f,a1=0.f,a2=0.f,a3=0.f;
  #pragma unroll
  for (int c=0;c<64;c+=4){
    a0 += wq[c+0]*bc(xq,c+0);
    a1 += wq[c+1]*bc(xq,c+1);
    a2 += wq[c+2]*bc(xq,c+2);
    a3 += wq[c+3]*bc(xq,c+3);
  }
  const float yq = (a0+a1)+(a2+a3);
  const int* ip = idx + (size_t)pt*KK;
  float acc = 0.f;
  for (int j=0;j<KK;j++){
    const int ij = ip[j];
    const float xg = xin[((size_t)(b*NN + ij))*64 + lane];
    const float d = xg - xq;
    float p0=0.f,p1=0.f,p2=0.f,p3=0.f;
    #pragma unroll
    for (int c=0;c<64;c+=4){
      p0 += wd[c+0]*bc(d,c+0);
      p1 += wd[c+1]*bc(d,c+1);
      p2 += wd[c+2]*bc(d,c+2);
      p3 += wd[c+3]*bc(d,c+3);
    }
    acc += lrelu((yq + ((p0+p1)+(p2+p3)))*s5o + t5o);
  }
  xout[(size_t)pt*64 + lane] = acc / 10.f;
}

// ---------------- G1: h6 = lrelu(W6@z), accumulate sum over N ----------------
__global__ __launch_bounds__(256) void g1_k(const float* __restrict__ W6,
   const float* __restrict__ x1t, const float* __restrict__ x2t, const float* __restrict__ x3t,
   const float* __restrict__ s6, const float* __restrict__ t6, float* __restrict__ gsum)
{
  __shared__ float Wl[16*132];
  __shared__ float Zl[16*260];
  const int tid = threadIdx.x;
  const int rb = blockIdx.x & 1;
  const int nt = (blockIdx.x >> 1) & 15;
  const int b  = blockIdx.x >> 5;
  const int r0 = rb*128;
  const int n0 = nt*256;
  const int ty = tid >> 4, tx = tid & 15;
  float acc[8][16];
  #pragma unroll
  for (int i=0;i<8;i++){
    #pragma unroll
    for (int j=0;j<16;j++) acc[i][j] = 0.f;
  }
  for (int kc=0; kc<12; kc++){
    __syncthreads();
    {
      const int r = tid >> 1, h = tid & 1;
      const float4* wp = (const float4*)(W6 + (size_t)(r0 + r)*192 + kc*16 + h*8);
      float tmp[8];
      *(float4*)&tmp[0] = wp[0];
      *(float4*)&tmp[4] = wp[1];
      #pragma unroll
      for (int u=0;u<8;u++) Wl[(h*8+u)*132 + r] = tmp[u];
    }
    {
      const float* arr = (kc < 4) ? x1t : (kc < 8) ? x2t : x3t;
      const int chofs = (kc & 3)*16;
      const float4* zp = (const float4*)(arr + ((size_t)(b*NN) + n0 + tid)*64 + chofs);
      float tmp[16];
      *(float4*)&tmp[0]  = zp[0];
      *(float4*)&tmp[4]  = zp[1];
      *(float4*)&tmp[8]  = zp[2];
      *(float4*)&tmp[12] = zp[3];
      #pragma unroll
      for (int u=0;u<16;u++) Zl[u*260 + tid] = tmp[u];
    }
    __syncthreads();
    #pragma unroll 4
    for (int k=0;k<16;k++){
      float wv[8], zv[16];
      *(float4*)&wv[0] = *(const float4*)(&Wl[k*132 + ty*8]);
      *(float4*)&wv[4] = *(const float4*)(&Wl[k*132 + ty*8 + 4]);
      #pragma unroll
      for (int jg=0;jg<4;jg++)
        *(float4*)&zv[jg*4] = *(const float4*)(&Zl[k*260 + jg*64 + tx*4]);
      #pragma unroll
      for (int i=0;i<8;i++){
        #pragma unroll
        for (int j=0;j<16;j++) acc[i][j] += wv[i]*zv[j];
      }
    }
  }
  #pragma unroll
  for (int i=0;i<8;i++){
    const int row = r0 + ty*8 + i;
    const float sv = s6[row], tv = t6[row];
    float sum = 0.f;
    #pragma unroll
    for (int j=0;j<16;j++) sum += lrelu(acc[i][j]*sv + tv);
    #pragma unroll
    for (int d=1; d<16; d<<=1) sum += __shfl_xor(sum, d, 64);
    if ((tid & 15) == 0) atomicAdd(&gsum[b*256 + row], sum);
  }
}

// ---------------- G2: c7 = W7[:, :256] @ (gsum/4096) ----------------
__global__ __launch_bounds__(256) void g2_k(const float* __restrict__ W7,
   const float* __restrict__ gsum, float* __restrict__ c7)
{
  const int b = blockIdx.x >> 1;
  const int o = (blockIdx.x & 1)*256 + threadIdx.x;
  const float* wr = W7 + (size_t)o*448;
  const float* gb = gsum + b*256;
  float a0=0.f,a1=0.f,a2=0.f,a3=0.f;
  #pragma unroll 4
  for (int c=0;c<256;c+=4){
    a0 += wr[c+0]*gb[c+0]; a1 += wr[c+1]*gb[c+1];
    a2 += wr[c+2]*gb[c+2]; a3 += wr[c+3]*gb[c+3];
  }
  c7[b*512+o] = ((a0+a1)+(a2+a3)) * (1.f/4096.f);
}

// ---------------- G3: h7 = lrelu((W7[:,256:]@z + c7)) -> max/sum over N ----------------
__global__ __launch_bounds__(256) void g3_k(const float* __restrict__ W7,
   const float* __restrict__ x1t, const float* __restrict__ x2t, const float* __restrict__ x3t,
   const float* __restrict__ c7, const float* __restrict__ s7, const float* __restrict__ t7,
   unsigned* __restrict__ x4e, float* __restrict__ x5s)
{
  __shared__ float Wl[16*132];
  __shared__ float Zl[16*260];
  const int tid = threadIdx.x;
  const int rb = blockIdx.x & 3;
  const int nt = (blockIdx.x >> 2) & 15;
  const int b  = blockIdx.x >> 6;
  const int r0 = rb*128;
  const int n0 = nt*256;
  const int ty = tid >> 4, tx = tid & 15;
  float acc[8][16];
  #pragma unroll
  for (int i=0;i<8;i++){
    #pragma unroll
    for (int j=0;j<16;j++) acc[i][j] = 0.f;
  }
  for (int kc=0; kc<12; kc++){
    __syncthreads();
    {
      const int r = tid >> 1, h = tid & 1;
      const float4* wp = (const float4*)(W7 + (size_t)(r0 + r)*448 + 256 + kc*16 + h*8);
      float tmp[8];
      *(float4*)&tmp[0] = wp[0];
      *(float4*)&tmp[4] = wp[1];
      #pragma unroll
      for (int u=0;u<8;u++) Wl[(h*8+u)*132 + r] = tmp[u];
    }
    {
      const float* arr = (kc < 4) ? x1t : (kc < 8) ? x2t : x3t;
      const int chofs = (kc & 3)*16;
      const float4* zp = (const float4*)(arr + ((size_t)(b*NN) + n0 + tid)*64 + chofs);
      float tmp[16];
      *(float4*)&tmp[0]  = zp[0];
      *(float4*)&tmp[4]  = zp[1];
      *(float4*)&tmp[8]  = zp[2];
      *(float4*)&tmp[12] = zp[3];
      #pragma unroll
      for (int u=0;u<16;u++) Zl[u*260 + tid] = tmp[u];
    }
    __syncthreads();
    #pragma unroll 4
    for (int k=0;k<16;k++){
      float wv[8], zv[16];
      *(float4*)&wv[0] = *(const float4*)(&Wl[k*132 + ty*8]);
      *(float4*)&wv[4] = *(const float4*)(&Wl[k*132 + ty*8 + 4]);
      #pragma unroll
      for (int jg=0;jg<4;jg++)
        *(float4*)&zv[jg*4] = *(const float4*)(&Zl[k*260 + jg*64 + tx*4]);
      #pragma unroll
      for (int i=0;i<8;i++){
        #pragma unroll
        for (int j=0;j<16;j++) acc[i][j] += wv[i]*zv[j];
      }
    }
  }
  #pragma unroll
  for (int i=0;i<8;i++){
    const int row = r0 + ty*8 + i;
    const float c7v = c7[b*512 + row];
    const float sv = s7[row], tv = t7[row];
    float mx = -__builtin_inff(), sum = 0.f;
    #pragma unroll
    for (int j=0;j<16;j++){
      float h = lrelu((acc[i][j] + c7v)*sv + tv);
      mx = fmaxf(mx, h); sum += h;
    }
    #pragma unroll
    for (int d=1; d<16; d<<=1){
      sum += __shfl_xor(sum, d, 64);
      mx = fmaxf(mx, __shfl_xor(mx, d, 64));
    }
    if ((tid & 15) == 0){
      atomicAdd(&x5s[b*512 + row], sum);
      atomicMax(&x4e[b*512 + row], fenc(mx));
    }
  }
}

// ---------------- G4: final linear ----------------
__global__ __launch_bounds__(128) void g4_k(const float* __restrict__ W8T,
  const unsigned* __restrict__ x4e, const float* __restrict__ x5s,
  const float* __restrict__ s8, const float* __restrict__ t8, float* __restrict__ out)
{
  const int b = blockIdx.x, j = threadIdx.x;
  float a0 = 0.f, a1 = 0.f;
  for (int o=0;o<512;o++){
    a0 += W8T[o*128 + j] * fdec(x4e[b*512 + o]);
    a1 += W8T[(512+o)*128 + j] * (x5s[b*512 + o] * (1.f/4096.f));
  }
  const float y = a0 + a1;
  out[b*128 + j] = lrelu(y*s8[j] + t8[j]);
}

extern "C" void kernel_launch(void* const* d_in, const int* in_sizes, int n_in,
                              void* d_out, int out_size, void* d_ws, size_t ws_size,
                              hipStream_t stream) {
  (void)in_sizes; (void)n_in; (void)out_size; (void)ws_size;
  const float* x  = (const float*)d_in[0];
  const float* W1 = (const float*)d_in[1];
  const float* W2 = (const float*)d_in[2];
  const float* W3 = (const float*)d_in[3];
  const float* W4 = (const float*)d_in[4];
  const float* W5 = (const float*)d_in[5];
  const float* W6 = (const float*)d_in[6];
  const float* W7 = (const float*)d_in[7];
  const float* W8 = (const float*)d_in[8];
  const float* s1 = (const float*)d_in[9];   const float* t1 = (const float*)d_in[10];
  const float* s2 = (const float*)d_in[11];  const float* t2 = (const float*)d_in[12];
  const float* s3 = (const float*)d_in[13];  const float* t3 = (const float*)d_in[14];
  const float* s4 = (const float*)d_in[15];  const float* t4 = (const float*)d_in[16];
  const float* s5 = (const float*)d_in[17];  const float* t5 = (const float*)d_in[18];
  const float* s6 = (const float*)d_in[19];  const float* t6 = (const float*)d_in[20];
  const float* s7 = (const float*)d_in[21];  const float* t7 = (const float*)d_in[22];
  const float* s8 = (const float*)d_in[23];  const float* t8 = (const float*)d_in[24];

  char* wsb = (char*)d_ws;
  size_t off = 0;
  auto alloc = [&](size_t bytes)->char* {
    char* p = wsb + off;
    off += (bytes + 255) & ~(size_t)255;
    return p;
  };
  int*      idx1 = (int*)alloc((size_t)BB*NN*KK*4);
  int*      idx2 = (int*)alloc((size_t)BB*NN*KK*4);
  int*      idx3 = (int*)alloc((size_t)BB*NN*KK*4);
  u64*      pkeys= (u64*)alloc((size_t)BB*NN*4*KK*8);
  float*    x1t  = (float*)alloc((size_t)BB*NN*64*4);
  float*    x2t  = (float*)alloc((size_t)BB*NN*64*4);
  float*    x3t  = (float*)alloc((size_t)BB*NN*64*4);
  unsigned short* Xh = (unsigned short*)alloc((size_t)BB*NN*64*2);
  unsigned short* Xl = (unsigned short*)alloc((size_t)BB*NN*64*2);
  float*    xxb  = (float*)alloc((size_t)BB*NN*4);
  float*    gsum = (float*)alloc((size_t)BB*256*4);
  unsigned* x4e  = (unsigned*)alloc((size_t)BB*512*4);
  float*    x5s  = (float*)alloc((size_t)BB*512*4);
  float*    c7   = (float*)alloc((size_t)BB*512*4);
  float*    W1T  = (float*)alloc(14*64*4);
  float*    W2T  = (float*)alloc(64*64*4);
  float*    W5T  = (float*)alloc(128*64*4);
  float*    W8T  = (float*)alloc(1024*128*4);
  unsigned short* W3dh = (unsigned short*)alloc(64*64*2);
  unsigned short* W3dl = (unsigned short*)alloc(64*64*2);
  unsigned short* W3qh = (unsigned short*)alloc(64*64*2);
  unsigned short* W3ql = (unsigned short*)alloc(64*64*2);
  unsigned short* W4h  = (unsigned short*)alloc(64*64*2);
  unsigned short* W4l  = (unsigned short*)alloc(64*64*2);

  prep_k<<<64,256,0,stream>>>(W1,W2,W3,W4,W5,W8, W1T,W2T,W5T,W8T, W3dh,W3dl,W3qh,W3ql,W4h,W4l);
  knn2d_k<<<BB*64*4,256,0,stream>>>(x, pkeys);
  kmerge_k<<<BB*NN/256,256,0,stream>>>(pkeys, idx1);
  edge1_k<<<BB*NN/4,256,0,stream>>>(x, idx1, W1T, W2T, s1,t1,s2,t2, x1t);
  cvt_k<<<BB*NN*8/256,256,0,stream>>>(x1t, Xh, Xl, xxb);
  knn64_k<<<BB*64*4,256,0,stream>>>(Xh, Xl, xxb, pkeys);
  kmerge_k<<<BB*NN/256,256,0,stream>>>(pkeys, idx2);
  edge2_k<<<BB*NN/8,256,0,stream>>>(x1t, idx2, W3dh,W3dl,W3qh,W3ql,W4h,W4l, s3,t3,s4,t4, x2t);
  cvt_k<<<BB*NN*8/256,256,0,stream>>>(x2t, Xh, Xl, xxb);
  knn64_k<<<BB*64*4,256,0,stream>>>(Xh, Xl, xxb, pkeys);
  kmerge_k<<<BB*NN/256,256,0,stream>>>(pkeys, idx3);
  edge3_k<<<BB*NN/4,256,0,stream>>>(x2t, idx3, W5T, s5,t5, x3t);
  hipMemsetAsync(gsum, 0, (size_t)BB*256*4 + (size_t)BB*512*4*2, stream);
  g1_k<<<256,256,0,stream>>>(W6, x1t,x2t,x3t, s6,t6, gsum);
  g2_k<<<16,256,0,stream>>>(W7, gsum, c7);
  g3_k<<<512,256,0,stream>>>(W7, x1t,x2t,x3t, c7, s7,t7, x4e, x5s);
  g4_k<<<BB,128,0,stream>>>(W8T, x4e, x5s, s8,t8, (float*)d_out);
}